// Round 16
// baseline (786.982 us; speedup 1.0000x reference)
//
#include <hip/hip_runtime.h>

typedef unsigned short u16;
typedef __attribute__((ext_vector_type(8))) short bf16x8;
typedef __attribute__((ext_vector_type(4))) float f32x4;

#define S_LEN 2048
#define D_MODEL 2048
#define NHEAD 32
#define DHEAD 64
#define FF_DIM 8192
#define NTOK 4096

#define GU_LDS_BYTES (2 * 65536)              // 128KB
#define DN_LDS_BYTES (2 * 65536)              // 128KB
#define QKV_SLOT_U16 (16384 + 3 * 4096)       // 28672 u16 = 56KB
#define QKV_LDS_BYTES (2 * QKV_SLOT_U16 * 2)  // 112KB

__device__ __forceinline__ u16 f2bf(float f) {
  union { float f; unsigned u; } v; v.f = f;
  unsigned r = v.u + 0x7fffu + ((v.u >> 16) & 1u);
  return (u16)(r >> 16);
}
__device__ __forceinline__ float bf2f(u16 b) {
  union { unsigned u; float f; } v; v.u = ((unsigned)b) << 16;
  return v.f;
}
__device__ __forceinline__ void gload_lds16(const void* g, void* l) {
  __builtin_amdgcn_global_load_lds(
      (const __attribute__((address_space(1))) void*)g,
      (__attribute__((address_space(3))) void*)l, 16, 0, 0);
}
__device__ __forceinline__ void barrier_f() {
  asm volatile("" ::: "memory");
  __builtin_amdgcn_s_barrier();
  asm volatile("" ::: "memory");
}

// ---------------- merged weight convert + rmsnorm1 (1 launch) ----------------
// tiles [0,16384): weight transpose/convert; [16384, 16384+NTOK): rmsnorm1 rows
__global__ __launch_bounds__(256) void wconv_all(
    const float* __restrict__ wq, const float* __restrict__ wk,
    const float* __restrict__ wv, const float* __restrict__ wo,
    const float* __restrict__ wg, const float* __restrict__ wu,
    const float* __restrict__ wd,
    u16* wq_t, u16* wk_t, u16* wv_t, u16* wo_t,
    u16* wg_t, u16* wu_t, u16* wd_t,
    const float* __restrict__ x, const float* __restrict__ n1w,
    u16* __restrict__ hn) {
  __shared__ float tile[64][65];
  const int t = blockIdx.x;
  const int tid = threadIdx.x;
  if (t >= 16384) {
    // ---- rmsnorm1 row ----
    const int row = t - 16384;
    const float* rp = x + (size_t)row * D_MODEL;
    float4 a = *(const float4*)&rp[tid * 8];
    float4 b = *(const float4*)&rp[tid * 8 + 4];
    float ss = a.x*a.x + a.y*a.y + a.z*a.z + a.w*a.w
             + b.x*b.x + b.y*b.y + b.z*b.z + b.w*b.w;
#pragma unroll
    for (int d = 1; d < 64; d <<= 1) ss += __shfl_xor(ss, d);
    if ((tid & 63) == 0) tile[0][tid >> 6] = ss;
    __syncthreads();
    const float tot = tile[0][0] + tile[0][1] + tile[0][2] + tile[0][3];
    const float rms = rsqrtf(tot * (1.f / (float)D_MODEL) + 1e-6f);
    float4 wa = *(const float4*)&n1w[tid * 8];
    float4 wb = *(const float4*)&n1w[tid * 8 + 4];
    uint4 o;
    o.x = (unsigned)f2bf(a.x * rms * wa.x) | ((unsigned)f2bf(a.y * rms * wa.y) << 16);
    o.y = (unsigned)f2bf(a.z * rms * wa.z) | ((unsigned)f2bf(a.w * rms * wa.w) << 16);
    o.z = (unsigned)f2bf(b.x * rms * wb.x) | ((unsigned)f2bf(b.y * rms * wb.y) << 16);
    o.w = (unsigned)f2bf(b.z * rms * wb.z) | ((unsigned)f2bf(b.w * rms * wb.w) << 16);
    *(uint4*)&hn[(size_t)row * D_MODEL + tid * 8] = o;
    return;
  }
  const float* in; u16* out; int Kd, Nd, lt;
  if (t < 4096) {
    const int m = t >> 10; lt = t & 1023;
    in  = m == 0 ? wq   : m == 1 ? wk   : m == 2 ? wv   : wo;
    out = m == 0 ? wq_t : m == 1 ? wk_t : m == 2 ? wv_t : wo_t;
    Kd = 2048; Nd = 2048;
  } else if (t < 12288) {
    const int m = (t - 4096) >> 12; lt = (t - 4096) & 4095;
    in = m == 0 ? wg : wu; out = m == 0 ? wg_t : wu_t;
    Kd = 2048; Nd = 8192;
  } else {
    lt = t - 12288; in = wd; out = wd_t; Kd = 8192; Nd = 2048;
  }
  const int ntx = Nd >> 6;
  const int n0 = (lt % ntx) * 64, k0 = (lt / ntx) * 64;
  const int r = tid >> 4, c4 = (tid & 15) * 4;
#pragma unroll
  for (int rr = 0; rr < 4; ++rr) {
    int kr = rr * 16 + r;
    float4 v = *(const float4*)&in[(size_t)(k0 + kr) * Nd + n0 + c4];
    tile[kr][c4 + 0] = v.x; tile[kr][c4 + 1] = v.y;
    tile[kr][c4 + 2] = v.z; tile[kr][c4 + 3] = v.w;
  }
  __syncthreads();
#pragma unroll
  for (int rr = 0; rr < 4; ++rr) {
    int nr = rr * 16 + r;
    uint2 o;
    o.x = (unsigned)f2bf(tile[c4 + 0][nr]) | ((unsigned)f2bf(tile[c4 + 1][nr]) << 16);
    o.y = (unsigned)f2bf(tile[c4 + 2][nr]) | ((unsigned)f2bf(tile[c4 + 3][nr]) << 16);
    *(uint2*)&out[(size_t)(n0 + nr) * Kd + k0 + c4] = o;
  }
}

// ---------------- staging: RN rows x 64 K into region (swizzled source) ----------------
template <int RN>
__device__ __forceinline__ void stage_op(const u16* src, int ldE,
                                         int row0, int ktbyte, u16* slot,
                                         int w, int lane) {
  constexpr int L = RN / 64;
#pragma unroll
  for (int l = 0; l < L; ++l) {
    const int dst = l * 8192 + w * 1024;
    const int dl = dst + lane * 16;
    const int srcb = dl ^ (((dl >> 7) & 7) << 4);
    const int row = srcb >> 7, colb = srcb & 127;
    gload_lds16((const char*)src + (size_t)(row0 + row) * ldE * 2 + ktbyte + colb,
                (char*)slot + dst);
  }
}

// ---------------- fused QKV GEMM: triple-B (BN=64) sharing one A staging ----------------
__global__ __launch_bounds__(512, 1) void gemm_qkv(
    const u16* __restrict__ A, const u16* __restrict__ Bq,
    const u16* __restrict__ Bk, const u16* __restrict__ Bv,
    int M, int N, int K,
    u16* __restrict__ oq, u16* __restrict__ ok, u16* __restrict__ ovt,
    const float* __restrict__ fc, const float* __restrict__ fs) {
  extern __shared__ u16 smem[];
  const int tid = threadIdx.x;
  const int w = tid >> 6, lane = tid & 63;
  const int nwg = gridDim.x, bid = blockIdx.x;
  const int sw = (bid & 7) * (nwg >> 3) + (bid >> 3);
  const int mtiles = M / 256;
  const int m0 = (sw % mtiles) * 256;
  const int n0 = (sw / mtiles) * 64;
  const int wm = w >> 1, wn = w & 1;
  const int KT = K / 64;
  const int ql = lane & 15, qh = (lane >> 4) * 16;
  f32x4 aq[4][2] = {}, ak[4][2] = {}, av[4][2] = {};

  auto stage = [&](int t, int slot) {
    u16* base = smem + slot * QKV_SLOT_U16;
    const int kb = t * 128;
    stage_op<256>(A,  K, m0, kb, base,          w, lane);
    stage_op<64>(Bq, K, n0, kb, base + 16384, w, lane);
    stage_op<64>(Bk, K, n0, kb, base + 20480, w, lane);
    stage_op<64>(Bv, K, n0, kb, base + 24576, w, lane);
  };

  stage(0, 0);
  for (int t = 0; t < KT; ++t) {
    if (t + 1 < KT) {
      stage(t + 1, (t + 1) & 1);
      asm volatile("s_waitcnt vmcnt(7)" ::: "memory");
    } else {
      asm volatile("s_waitcnt vmcnt(0)" ::: "memory");
    }
    __builtin_amdgcn_s_barrier();
    asm volatile("" ::: "memory");

    const u16* sA = smem + (t & 1) * QKV_SLOT_U16;
    const u16* sQ = sA + 16384;
    const u16* sK = sA + 20480;
    const u16* sV = sA + 24576;
#pragma unroll
    for (int kk = 0; kk < 2; ++kk) {
      bf16x8 af[4], bq[2], bk[2], bv[2];
      const int cb = kk * 64 + qh;
#pragma unroll
      for (int i = 0; i < 4; ++i) {
        const int row = wm * 64 + i * 16 + ql;
        af[i] = *(const bf16x8*)((const char*)sA + (((row << 7) + cb) ^ ((row & 7) << 4)));
      }
#pragma unroll
      for (int j = 0; j < 2; ++j) {
        const int row = wn * 32 + j * 16 + ql;
        const int byt = (((row << 7) + cb) ^ ((row & 7) << 4));
        bq[j] = *(const bf16x8*)((const char*)sQ + byt);
        bk[j] = *(const bf16x8*)((const char*)sK + byt);
        bv[j] = *(const bf16x8*)((const char*)sV + byt);
      }
      __builtin_amdgcn_s_setprio(1);
#pragma unroll
      for (int i = 0; i < 4; ++i)
#pragma unroll
        for (int j = 0; j < 2; ++j) {
          aq[i][j] = __builtin_amdgcn_mfma_f32_16x16x32_bf16(af[i], bq[j], aq[i][j], 0, 0, 0);
          ak[i][j] = __builtin_amdgcn_mfma_f32_16x16x32_bf16(af[i], bk[j], ak[i][j], 0, 0, 0);
          av[i][j] = __builtin_amdgcn_mfma_f32_16x16x32_bf16(af[i], bv[j], av[i][j], 0, 0, 0);
        }
      __builtin_amdgcn_s_setprio(0);
    }
    __builtin_amdgcn_s_barrier();
    asm volatile("" ::: "memory");
  }

  const int rbase = (lane >> 4) * 4;
#pragma unroll
  for (int i = 0; i < 4; ++i) {
#pragma unroll
    for (int j = 0; j < 2; ++j) {
      const int grow0 = m0 + wm * 64 + i * 16 + rbase;
      const int c = n0 + wn * 32 + j * 16 + ql;
      const int i2 = (c & 63) >> 1;
      const int odd = c & 1;
      {
        const int b = grow0 >> 11, s4 = grow0 & (S_LEN - 1);
        const int h = c >> 6, dh = c & 63;
        uint2 ov;
        ov.x = (unsigned)f2bf(av[i][j][0]) | ((unsigned)f2bf(av[i][j][1]) << 16);
        ov.y = (unsigned)f2bf(av[i][j][2]) | ((unsigned)f2bf(av[i][j][3]) << 16);
        *(uint2*)&ovt[((((size_t)b * NHEAD + h) * DHEAD + dh) << 11) + s4] = ov;
      }
#pragma unroll
      for (int r = 0; r < 4; ++r) {
        const int grow = grow0 + r;
        const int s4 = grow & (S_LEN - 1);
        const float cs = fc[s4 * 32 + i2], sn = fs[s4 * 32 + i2];
        {
          const float v = aq[i][j][r];
          const float p = __shfl_xor(v, 1);
          const float outv = odd ? (p * sn + v * cs) : (v * cs - p * sn);
          oq[(size_t)grow * D_MODEL + c] = f2bf(outv);
        }
        {
          const float v = ak[i][j][r];
          const float p = __shfl_xor(v, 1);
          const float outv = odd ? (p * sn + v * cs) : (v * cs - p * sn);
          ok[(size_t)grow * D_MODEL + c] = f2bf(outv);
        }
      }
    }
  }
}

// ---------------- fused gate+up GEMM: 4-phase, all stages at P0, single drain at P3 ----------------
__global__ __launch_bounds__(512, 1) void gemm_gu(
    const u16* __restrict__ A, const u16* __restrict__ Bg, const u16* __restrict__ Bu,
    int M, int N, int K, u16* __restrict__ o0) {
  extern __shared__ u16 smem[];
  const int tid = threadIdx.x;
  const int w = tid >> 6, lane = tid & 63;
  const int nwg = gridDim.x, bid = blockIdx.x;
  const int sw = (bid & 7) * (nwg >> 3) + (bid >> 3);
  const int mtiles = M / 256;
  const int m0 = (sw % mtiles) * 256;
  const int n0 = (sw / mtiles) * 128;
  const int wm = w >> 1, wn = w & 1;
  const int KT = K / 64;
  const int ql = lane & 15, qh = (lane >> 4) * 16;
  f32x4 accg[4][4] = {}, accu[4][4] = {};

  int abyt[4][2], bbyt[4][2];
#pragma unroll
  for (int i = 0; i < 4; ++i)
#pragma unroll
    for (int kk = 0; kk < 2; ++kk) {
      const int ra = wm * 64 + i * 16 + ql;
      abyt[i][kk] = ((ra << 7) + kk * 64 + qh) ^ ((ra & 7) << 4);
      const int rb = wn * 64 + i * 16 + ql;
      bbyt[i][kk] = ((rb << 7) + kk * 64 + qh) ^ ((rb & 7) << 4);
    }

  auto stage_all = [&](int t, int slot) {   // A(4) + Bg(2) + Bu(2) = 8 loads
    u16* base = smem + slot * 32768;
    stage_op<256>(A,  K, m0, t * 128, base,         w, lane);
    stage_op<128>(Bg, K, n0, t * 128, base + 16384, w, lane);
    stage_op<128>(Bu, K, n0, t * 128, base + 24576, w, lane);
  };

  stage_all(0, 0);
  asm volatile("s_waitcnt vmcnt(0)" ::: "memory");
  barrier_f();

  for (int t = 0; t < KT; ++t) {
    const bool last = (t == KT - 1);
    const char* sA = (const char*)smem + (t & 1) * 65536;
    const char* sG = sA + 32768;
    const char* sU = sA + 49152;
    bf16x8 af[4], bb[4];
    // ---- P0: af.bg kk0 | issue ALL of tile t+1 ----
#pragma unroll
    for (int i = 0; i < 4; ++i) af[i] = *(const bf16x8*)(sA + abyt[i][0]);
#pragma unroll
    for (int j = 0; j < 4; ++j) bb[j] = *(const bf16x8*)(sG + bbyt[j][0]);
    if (!last) stage_all(t + 1, (t + 1) & 1);
    barrier_f();
    __builtin_amdgcn_s_setprio(1);
#pragma unroll
    for (int i = 0; i < 4; ++i)
#pragma unroll
      for (int j = 0; j < 4; ++j)
        accg[i][j] = __builtin_amdgcn_mfma_f32_16x16x32_bf16(af[i], bb[j], accg[i][j], 0, 0, 0);
    __builtin_amdgcn_s_setprio(0);
    barrier_f();
    // ---- P1: af.bu kk0 ----
#pragma unroll
    for (int j = 0; j < 4; ++j) bb[j] = *(const bf16x8*)(sU + bbyt[j][0]);
    barrier_f();
    __builtin_amdgcn_s_setprio(1);
#pragma unroll
    for (int i = 0; i < 4; ++i)
#pragma unroll
      for (int j = 0; j < 4; ++j)
        accu[i][j] = __builtin_amdgcn_mfma_f32_16x16x32_bf16(af[i], bb[j], accu[i][j], 0, 0, 0);
    __builtin_amdgcn_s_setprio(0);
    barrier_f();
    // ---- P2: af.bg kk1 ----
#pragma unroll
    for (int i = 0; i < 4; ++i) af[i] = *(const bf16x8*)(sA + abyt[i][1]);
#pragma unroll
    for (int j = 0; j < 4; ++j) bb[j] = *(const bf16x8*)(sG + bbyt[j][1]);
    barrier_f();
    __builtin_amdgcn_s_setprio(1);
#pragma unroll
    for (int i = 0; i < 4; ++i)
#pragma unroll
      for (int j = 0; j < 4; ++j)
        accg[i][j] = __builtin_amdgcn_mfma_f32_16x16x32_bf16(af[i], bb[j], accg[i][j], 0, 0, 0);
    __builtin_amdgcn_s_setprio(0);
    barrier_f();
    // ---- P3: af.bu kk1 | single drain (3 phases of cover for tile t+1) ----
#pragma unroll
    for (int j = 0; j < 4; ++j) bb[j] = *(const bf16x8*)(sU + bbyt[j][1]);
    asm volatile("s_waitcnt vmcnt(0)" ::: "memory");
    barrier_f();
    __builtin_amdgcn_s_setprio(1);
#pragma unroll
    for (int i = 0; i < 4; ++i)
#pragma unroll
      for (int j = 0; j < 4; ++j)
        accu[i][j] = __builtin_amdgcn_mfma_f32_16x16x32_bf16(af[i], bb[j], accu[i][j], 0, 0, 0);
    __builtin_amdgcn_s_setprio(0);
    barrier_f();
  }

  const int rbase = (lane >> 4) * 4;
#pragma unroll
  for (int i = 0; i < 4; ++i) {
#pragma unroll
    for (int j = 0; j < 4; ++j) {
      const int grow0 = m0 + wm * 64 + i * 16 + rbase;
      const int gcol = n0 + wn * 64 + j * 16 + ql;
#pragma unroll
      for (int r = 0; r < 4; ++r) {
        const float g = accg[i][j][r];
        const float u = accu[i][j][r];
        const float sg = g / (1.f + __expf(-g));
        o0[(size_t)(grow0 + r) * N + gcol] = f2bf(sg * u);
      }
    }
  }
}

// ---------------- split-K GEMM: ring-2, 256x256, split-K=2, bf16 partials ----------------
__global__ __launch_bounds__(512, 1) void gemm_dn(
    const u16* __restrict__ A, const u16* __restrict__ Bt,
    int M, int N, int Kld, u16* __restrict__ pbuf) {
  extern __shared__ u16 smem[];
  const int tid = threadIdx.x;
  const int w = tid >> 6, lane = tid & 63;
  const int nwg = gridDim.x, bid = blockIdx.x;
  const int sw = (bid & 7) * (nwg >> 3) + (bid >> 3);
  const int mtiles = M / 256;
  const int tilesPerSplit = mtiles * (N / 256);
  const int split = sw / tilesPerSplit;
  const int tt = sw % tilesPerSplit;
  const int m0 = (tt % mtiles) * 256;
  const int n0 = (tt / mtiles) * 256;
  const u16* Ap = A + (size_t)split * (Kld / 2);
  const u16* Bp = Bt + (size_t)split * (Kld / 2);
  u16* op = pbuf + (size_t)split * M * N;
  const int wm = w >> 2, wn = w & 3;
  const int KT = (Kld / 2) / 64;
  const int ql = lane & 15, qh = (lane >> 4) * 16;
  f32x4 acc[8][4] = {};

  auto stage = [&](int t, int slot) {
    u16* base = smem + slot * 32768;
    const int kb = t * 128;
    stage_op<256>(Ap, Kld, m0, kb, base,         w, lane);
    stage_op<256>(Bp, Kld, n0, kb, base + 16384, w, lane);
  };

  stage(0, 0);
  for (int t = 0; t < KT; ++t) {
    if (t + 1 < KT) {
      stage(t + 1, (t + 1) & 1);
      asm volatile("s_waitcnt vmcnt(8)" ::: "memory");
    } else {
      asm volatile("s_waitcnt vmcnt(0)" ::: "memory");
    }
    __builtin_amdgcn_s_barrier();
    asm volatile("" ::: "memory");

    const u16* sA = smem + (t & 1) * 32768;
    const u16* sB = sA + 16384;
#pragma unroll
    for (int kk = 0; kk < 2; ++kk) {
      bf16x8 af[8], bq[4];
      const int cb = kk * 64 + qh;
#pragma unroll
      for (int i = 0; i < 8; ++i) {
        const int row = wm * 128 + i * 16 + ql;
        af[i] = *(const bf16x8*)((const char*)sA + (((row << 7) + cb) ^ ((row & 7) << 4)));
      }
#pragma unroll
      for (int j = 0; j < 4; ++j) {
        const int row = wn * 64 + j * 16 + ql;
        bq[j] = *(const bf16x8*)((const char*)sB + (((row << 7) + cb) ^ ((row & 7) << 4)));
      }
      __builtin_amdgcn_s_setprio(1);
#pragma unroll
      for (int i = 0; i < 8; ++i)
#pragma unroll
        for (int j = 0; j < 4; ++j)
          acc[i][j] = __builtin_amdgcn_mfma_f32_16x16x32_bf16(af[i], bq[j], acc[i][j], 0, 0, 0);
      __builtin_amdgcn_s_setprio(0);
    }
    __builtin_amdgcn_s_barrier();
    asm volatile("" ::: "memory");
  }

  const int rbase = (lane >> 4) * 4;
#pragma unroll
  for (int i = 0; i < 8; ++i) {
#pragma unroll
    for (int j = 0; j < 4; ++j) {
      const int grow0 = m0 + wm * 128 + i * 16 + rbase;
      const int gcol = n0 + wn * 64 + j * 16 + ql;
#pragma unroll
      for (int r = 0; r < 4; ++r)
        op[(size_t)(grow0 + r) * N + gcol] = f2bf(acc[i][j][r]);
    }
  }
}

// ---------------- down combine: out += p0 + p1 (bf16 partials) ----------------
__global__ __launch_bounds__(256) void combine_kernel(
    const u16* __restrict__ p0, const u16* __restrict__ p1, float* __restrict__ out) {
  const size_t idx = ((size_t)blockIdx.x * 256 + threadIdx.x) * 8;
  bf16x8 a = *(const bf16x8*)&p0[idx];
  bf16x8 b = *(const bf16x8*)&p1[idx];
  float4 c0 = *(const float4*)&out[idx];
  float4 c1 = *(const float4*)&out[idx + 4];
  c0.x += bf2f((u16)a[0]) + bf2f((u16)b[0]);
  c0.y += bf2f((u16)a[1]) + bf2f((u16)b[1]);
  c0.z += bf2f((u16)a[2]) + bf2f((u16)b[2]);
  c0.w += bf2f((u16)a[3]) + bf2f((u16)b[3]);
  c1.x += bf2f((u16)a[4]) + bf2f((u16)b[4]);
  c1.y += bf2f((u16)a[5]) + bf2f((u16)b[5]);
  c1.z += bf2f((u16)a[6]) + bf2f((u16)b[6]);
  c1.w += bf2f((u16)a[7]) + bf2f((u16)b[7]);
  *(float4*)&out[idx] = c0;
  *(float4*)&out[idx + 4] = c1;
}

// ---------------- O-proj combine + residual + fused rmsnorm2 ----------------
__global__ __launch_bounds__(256) void combine_o_norm(
    const u16* __restrict__ p0, const u16* __restrict__ p1,
    const float* __restrict__ x, const float* __restrict__ wt,
    float* __restrict__ out, u16* __restrict__ hn) {
  const int row = blockIdx.x;
  const int tid = threadIdx.x;
  const size_t base = (size_t)row * D_MODEL + tid * 8;
  bf16x8 a = *(const bf16x8*)&p0[base];
  bf16x8 b = *(const bf16x8*)&p1[base];
  float4 x0 = *(const float4*)&x[base];
  float4 x1 = *(const float4*)&x[base + 4];
  float c[8];
  c[0] = x0.x + bf2f((u16)a[0]) + bf2f((u16)b[0]);
  c[1] = x0.y + bf2f((u16)a[1]) + bf2f((u16)b[1]);
  c[2] = x0.z + bf2f((u16)a[2]) + bf2f((u16)b[2]);
  c[3] = x0.w + bf2f((u16)a[3]) + bf2f((u16)b[3]);
  c[4] = x1.x + bf2f((u16)a[4]) + bf2f((u16)b[4]);
  c[5] = x1.y + bf2f((u16)a[5]) + bf2f((u16)b[5]);
  c[6] = x1.z + bf2f((u16)a[6]) + bf2f((u16)b[6]);
  c[7] = x1.w + bf2f((u16)a[7]) + bf2f((u16)b[7]);
  float4 o0 = {c[0], c[1], c[2], c[3]};
  float4 o1 = {c[4], c[5], c[6], c[7]};
  *(float4*)&out[base] = o0;
  *(float4*)&out[base + 4] = o1;
  float ss = 0.f;
#pragma unroll
  for (int e = 0; e < 8; ++e) ss += c[e] * c[e];
#pragma unroll
  for (int d = 1; d < 64; d <<= 1) ss += __shfl_xor(ss, d);
  __shared__ float red[4];
  if ((tid & 63) == 0) red[tid >> 6] = ss;
  __syncthreads();
  const float tot = red[0] + red[1] + red[2] + red[3];
  const float rms = rsqrtf(tot * (1.f / (float)D_MODEL) + 1e-6f);
  float4 wa = *(const float4*)&wt[tid * 8];
  float4 wb = *(const float4*)&wt[tid * 8 + 4];
  uint4 o;
  o.x = (unsigned)f2bf(c[0] * rms * wa.x) | ((unsigned)f2bf(c[1] * rms * wa.y) << 16);
  o.y = (unsigned)f2bf(c[2] * rms * wa.z) | ((unsigned)f2bf(c[3] * rms * wa.w) << 16);
  o.z = (unsigned)f2bf(c[4] * rms * wb.x) | ((unsigned)f2bf(c[5] * rms * wb.y) << 16);
  o.w = (unsigned)f2bf(c[6] * rms * wb.z) | ((unsigned)f2bf(c[7] * rms * wb.w) << 16);
  *(uint4*)&hn[base] = o;
}

// ---------------- Flash attention (causal), swapped-QK^T, swizzled, ring-2, defer-max ----------------
__global__ __launch_bounds__(256) void attn_kernel(
    const u16* __restrict__ q, const u16* __restrict__ k,
    const u16* __restrict__ vt, u16* __restrict__ o) {
  __shared__ u16 lKV[2][128 * 64];
  __shared__ u16 lP[4][32 * 64];
  const int tid = threadIdx.x, w = tid >> 6, lane = tid & 63;
  const int ql = lane & 15, qh16 = (lane >> 4) * 16, rbase = (lane >> 4) * 4;
  const int bx = (int)gridDim.x - 1 - (int)blockIdx.x;
  const int bh = blockIdx.y, b = bh >> 5, h = bh & 31;
  const int q0 = bx * 128;
  const int nt = 2 * bx + 2;
  const char* kbase = (const char*)(k + ((size_t)b * S_LEN) * D_MODEL + h * DHEAD);
  const char* vbase = (const char*)(vt + (size_t)bh * DHEAD * S_LEN);

  bf16x8 qf[2][2];
#pragma unroll
  for (int i = 0; i < 2; ++i) {
    const size_t tok = (size_t)b * S_LEN + q0 + w * 32 + i * 16 + ql;
#pragma unroll
    for (int kk = 0; kk < 2; ++kk) {
      bf16x8 v = *(const bf16x8*)&q[tok * D_MODEL + h * DHEAD + kk * 32 + (lane >> 4) * 8];
#pragma unroll
      for (int e = 0; e < 8; ++e) v[e] = (short)f2bf(bf2f((u16)v[e]) * 0.125f);
      qf[i][kk] = v;
    }
  }

  float m[2] = {-1e30f, -1e30f}, l[2] = {0.f, 0.f};
  f32x4 oacc[2][4] = {};

  auto stage = [&](int kt, int slot) {
    const int s0 = kt * 64;
#pragma unroll
    for (int lo = 0; lo < 2; ++lo) {
      const int dst = lo * 4096 + w * 1024;
      const int dl = dst + lane * 16;
      const int srcb = dl ^ (((dl >> 7) & 7) << 4);
      const int row = srcb >> 7, colb = srcb & 127;
      gload_lds16(kbase + (size_t)(s0 + row) * (D_MODEL * 2) + colb,
                  (char*)&lKV[slot][0] + dst);
    }
#pragma unroll
    for (int lo = 0; lo < 2; ++lo) {
      const int dst = lo * 4096 + w * 1024;
      const int dl = dst + lane * 16;
      const int srcb = dl ^ (((dl >> 7) & 7) << 4);
      const int row = srcb >> 7, colb = srcb & 127;
      gload_lds16(vbase + (size_t)row * (S_LEN * 2) + (size_t)s0 * 2 + colb,
                  (char*)&lKV[slot][64 * 64] + dst);
    }
  };

  stage(0, 0);
  for (int kt = 0; kt < nt; ++kt) {
    if (kt + 1 < nt) {
      stage(kt + 1, (kt + 1) & 1);
      asm volatile("s_waitcnt vmcnt(4)" ::: "memory");
    } else {
      asm volatile("s_waitcnt vmcnt(0)" ::: "memory");
    }
    __builtin_amdgcn_s_barrier();
    asm volatile("" ::: "memory");

    const u16* sK = &lKV[kt & 1][0];
    const u16* sV = &lKV[kt & 1][64 * 64];
    const int s0 = kt * 64;

    f32x4 scT[2][4] = {};
#pragma unroll
    for (int kk = 0; kk < 2; ++kk) {
#pragma unroll
      for (int j = 0; j < 4; ++j) {
        const int row = j * 16 + ql;
        bf16x8 kf = *(const bf16x8*)((const char*)sK +
                      (((row << 7) + kk * 64 + qh16) ^ ((row & 7) << 4)));
#pragma unroll
        for (int i = 0; i < 2; ++i)
          scT[i][j] = __builtin_amdgcn_mfma_f32_16x16x32_bf16(kf, qf[i][kk], scT[i][j], 0, 0, 0);
      }
    }
    const bool diag = (s0 + 63 > q0);
#pragma unroll
    for (int i = 0; i < 2; ++i) {
      const int qrow = q0 + w * 32 + i * 16 + ql;
      if (diag) {
#pragma unroll
        for (int j = 0; j < 4; ++j)
#pragma unroll
          for (int r = 0; r < 4; ++r)
            if (s0 + j * 16 + rbase + r > qrow) scT[i][j][r] = -1e30f;
      }
      float mx = scT[i][0][0];
#pragma unroll
      for (int j = 0; j < 4; ++j)
#pragma unroll
        for (int r = 0; r < 4; ++r) mx = fmaxf(mx, scT[i][j][r]);
      mx = fmaxf(mx, __shfl_xor(mx, 16));
      mx = fmaxf(mx, __shfl_xor(mx, 32));
      float alpha = 1.f;
      if (!__all(mx - m[i] <= 8.f)) {
        const float mnew = fmaxf(m[i], mx);
        alpha = __expf(m[i] - mnew);
        m[i] = mnew;
#pragma unroll
        for (int rr = 0; rr < 4; ++rr) {
          const float ar = __shfl(alpha, rbase + rr);
#pragma unroll
          for (int j = 0; j < 4; ++j) oacc[i][j][rr] *= ar;
        }
      }
      float rs = 0.f;
#pragma unroll
      for (int j = 0; j < 4; ++j)
#pragma unroll
        for (int r = 0; r < 4; ++r) {
          const float p = __expf(scT[i][j][r] - m[i]);
          scT[i][j][r] = p;
          rs += p;
        }
      rs += __shfl_xor(rs, 16);
      rs += __shfl_xor(rs, 32);
      l[i] = l[i] * alpha + rs;
      const int prow = i * 16 + ql;
      const int pb = prow << 7;
      const int swz = (prow & 7) << 4;
#pragma unroll
      for (int j = 0; j < 4; ++j) {
#pragma unroll
        for (int rp = 0; rp < 2; ++rp) {
          const int col = j * 16 + rbase + rp * 2;
          unsigned pk = (unsigned)f2bf(scT[i][j][rp * 2]) |
                        ((unsigned)f2bf(scT[i][j][rp * 2 + 1]) << 16);
          *(unsigned*)((char*)lP[w] + ((pb + col * 2) ^ swz)) = pk;
        }
      }
    }
#pragma unroll
    for (int i = 0; i < 2; ++i) {
      const int arow = i * 16 + ql;
#pragma unroll
      for (int kk = 0; kk < 2; ++kk) {
        bf16x8 pa = *(const bf16x8*)((const char*)lP[w] +
                      (((arow << 7) + kk * 64 + qh16) ^ ((arow & 7) << 4)));
#pragma unroll
        for (int j = 0; j < 4; ++j) {
          const int vrow = j * 16 + ql;
          bf16x8 bv = *(const bf16x8*)((const char*)sV +
                        (((vrow << 7) + kk * 64 + qh16) ^ ((vrow & 7) << 4)));
          oacc[i][j] = __builtin_amdgcn_mfma_f32_16x16x32_bf16(pa, bv, oacc[i][j], 0, 0, 0);
        }
      }
    }
    __builtin_amdgcn_s_barrier();
    asm volatile("" ::: "memory");
  }
#pragma unroll
  for (int i = 0; i < 2; ++i) {
#pragma unroll
    for (int rr = 0; rr < 4; ++rr) {
      const float linv = 1.f / __shfl(l[i], rbase + rr);
      const size_t tok = (size_t)b * S_LEN + q0 + w * 32 + i * 16 + rbase + rr;
#pragma unroll
      for (int j = 0; j < 4; ++j)
        o[tok * D_MODEL + h * DHEAD + j * 16 + ql] = f2bf(oacc[i][j][rr] * linv);
    }
  }
}

// ---------------- host ----------------
extern "C" void kernel_launch(void* const* d_in, const int* in_sizes, int n_in,
                              void* d_out, int out_size, void* d_ws, size_t ws_size,
                              hipStream_t stream) {
  (void)in_sizes; (void)n_in; (void)out_size; (void)ws_size;
  const float* x  = (const float*)d_in[0];
  const float* fc = (const float*)d_in[1];
  const float* fs = (const float*)d_in[2];
  const float* wq = (const float*)d_in[4];
  const float* wk = (const float*)d_in[5];
  const float* wv = (const float*)d_in[6];
  const float* wo = (const float*)d_in[7];
  const float* wg = (const float*)d_in[8];
  const float* wu = (const float*)d_in[9];
  const float* wd = (const float*)d_in[10];
  const float* n1 = (const float*)d_in[11];
  const float* n2 = (const float*)d_in[12];
  float* out = (float*)d_out;

  char* ws = (char*)d_ws;
  size_t off = 0;
  auto alloc = [&](size_t bytes) { void* p = ws + off; off += (bytes + 255) & ~(size_t)255; return p; };
  u16* wq_t = (u16*)alloc((size_t)D_MODEL * D_MODEL * 2);
  u16* wk_t = (u16*)alloc((size_t)D_MODEL * D_MODEL * 2);
  u16* wv_t = (u16*)alloc((size_t)D_MODEL * D_MODEL * 2);
  u16* wo_t = (u16*)alloc((size_t)D_MODEL * D_MODEL * 2);
  u16* wg_t = (u16*)alloc((size_t)D_MODEL * FF_DIM * 2);
  u16* wu_t = (u16*)alloc((size_t)D_MODEL * FF_DIM * 2);
  u16* wd_t = (u16*)alloc((size_t)FF_DIM * D_MODEL * 2);
  u16* hn   = (u16*)alloc((size_t)NTOK * D_MODEL * 2);
  u16* qb   = (u16*)alloc((size_t)NTOK * D_MODEL * 2);
  u16* kb   = (u16*)alloc((size_t)NTOK * D_MODEL * 2);
  u16* vtb  = (u16*)alloc((size_t)NTOK * D_MODEL * 2);
  u16* ao   = (u16*)alloc((size_t)NTOK * D_MODEL * 2);
  u16* gt   = (u16*)alloc((size_t)NTOK * FF_DIM * 2);
  u16* pbuf = qb;   // bf16 split-K partials reuse dead qb/kb region

  // weight conversions + rmsnorm1 in one launch (16384 + 4096 blocks)
  wconv_all<<<16384 + NTOK, 256, 0, stream>>>(wq, wk, wv, wo, wg, wu, wd,
                                              wq_t, wk_t, wv_t, wo_t, wg_t, wu_t, wd_t,
                                              x, n1, hn);
  gemm_qkv<<<512, 512, QKV_LDS_BYTES, stream>>>(hn, wq_t, wk_t, wv_t,
                                                NTOK, D_MODEL, D_MODEL,
                                                qb, kb, vtb, fc, fs);
  attn_kernel<<<dim3(16, 64), 256, 0, stream>>>(qb, kb, vtb, ao);
  gemm_dn<<<256, 512, DN_LDS_BYTES, stream>>>(ao, wo_t, NTOK, D_MODEL, D_MODEL, pbuf);
  combine_o_norm<<<NTOK, 256, 0, stream>>>(pbuf, pbuf + (size_t)NTOK * D_MODEL,
                                           x, n2, out, hn);
  gemm_gu<<<1024, 512, GU_LDS_BYTES, stream>>>(hn, wg_t, wu_t, NTOK, FF_DIM, D_MODEL, gt);
  gemm_dn<<<256, 512, DN_LDS_BYTES, stream>>>(gt, wd_t, NTOK, D_MODEL, FF_DIM, pbuf);
  combine_kernel<<<(NTOK * D_MODEL) / (256 * 8), 256, 0, stream>>>(
      pbuf, pbuf + (size_t)NTOK * D_MODEL, out);
}

// Round 17
// 780.758 us; speedup vs baseline: 1.0080x; 1.0080x over previous
//
#include <hip/hip_runtime.h>

typedef unsigned short u16;
typedef __attribute__((ext_vector_type(8))) short bf16x8;
typedef __attribute__((ext_vector_type(4))) float f32x4;

#define S_LEN 2048
#define D_MODEL 2048
#define NHEAD 32
#define DHEAD 64
#define FF_DIM 8192
#define NTOK 4096

#define GU_LDS_BYTES (2 * 65536)              // 128KB
#define DN_LDS_BYTES (2 * 65536)              // 128KB
#define QKV_SLOT_U16 (16384 + 3 * 4096)       // 28672 u16 = 56KB
#define QKV_LDS_BYTES (2 * QKV_SLOT_U16 * 2)  // 112KB

__device__ __forceinline__ u16 f2bf(float f) {
  union { float f; unsigned u; } v; v.f = f;
  unsigned r = v.u + 0x7fffu + ((v.u >> 16) & 1u);
  return (u16)(r >> 16);
}
__device__ __forceinline__ float bf2f(u16 b) {
  union { unsigned u; float f; } v; v.u = ((unsigned)b) << 16;
  return v.f;
}
__device__ __forceinline__ void gload_lds16(const void* g, void* l) {
  __builtin_amdgcn_global_load_lds(
      (const __attribute__((address_space(1))) void*)g,
      (__attribute__((address_space(3))) void*)l, 16, 0, 0);
}
__device__ __forceinline__ void barrier_f() {
  asm volatile("" ::: "memory");
  __builtin_amdgcn_s_barrier();
  asm volatile("" ::: "memory");
}

// ---------------- merged weight convert + rmsnorm1 (1 launch) ----------------
// tiles [0,16384): weight transpose/convert; [16384, 16384+NTOK): rmsnorm1 rows
__global__ __launch_bounds__(256) void wconv_all(
    const float* __restrict__ wq, const float* __restrict__ wk,
    const float* __restrict__ wv, const float* __restrict__ wo,
    const float* __restrict__ wg, const float* __restrict__ wu,
    const float* __restrict__ wd,
    u16* wq_t, u16* wk_t, u16* wv_t, u16* wo_t,
    u16* wg_t, u16* wu_t, u16* wd_t,
    const float* __restrict__ x, const float* __restrict__ n1w,
    u16* __restrict__ hn) {
  __shared__ float tile[64][65];
  const int t = blockIdx.x;
  const int tid = threadIdx.x;
  if (t >= 16384) {
    // ---- rmsnorm1 row ----
    const int row = t - 16384;
    const float* rp = x + (size_t)row * D_MODEL;
    float4 a = *(const float4*)&rp[tid * 8];
    float4 b = *(const float4*)&rp[tid * 8 + 4];
    float ss = a.x*a.x + a.y*a.y + a.z*a.z + a.w*a.w
             + b.x*b.x + b.y*b.y + b.z*b.z + b.w*b.w;
#pragma unroll
    for (int d = 1; d < 64; d <<= 1) ss += __shfl_xor(ss, d);
    if ((tid & 63) == 0) tile[0][tid >> 6] = ss;
    __syncthreads();
    const float tot = tile[0][0] + tile[0][1] + tile[0][2] + tile[0][3];
    const float rms = rsqrtf(tot * (1.f / (float)D_MODEL) + 1e-6f);
    float4 wa = *(const float4*)&n1w[tid * 8];
    float4 wb = *(const float4*)&n1w[tid * 8 + 4];
    uint4 o;
    o.x = (unsigned)f2bf(a.x * rms * wa.x) | ((unsigned)f2bf(a.y * rms * wa.y) << 16);
    o.y = (unsigned)f2bf(a.z * rms * wa.z) | ((unsigned)f2bf(a.w * rms * wa.w) << 16);
    o.z = (unsigned)f2bf(b.x * rms * wb.x) | ((unsigned)f2bf(b.y * rms * wb.y) << 16);
    o.w = (unsigned)f2bf(b.z * rms * wb.z) | ((unsigned)f2bf(b.w * rms * wb.w) << 16);
    *(uint4*)&hn[(size_t)row * D_MODEL + tid * 8] = o;
    return;
  }
  const float* in; u16* out; int Kd, Nd, lt;
  if (t < 4096) {
    const int m = t >> 10; lt = t & 1023;
    in  = m == 0 ? wq   : m == 1 ? wk   : m == 2 ? wv   : wo;
    out = m == 0 ? wq_t : m == 1 ? wk_t : m == 2 ? wv_t : wo_t;
    Kd = 2048; Nd = 2048;
  } else if (t < 12288) {
    const int m = (t - 4096) >> 12; lt = (t - 4096) & 4095;
    in = m == 0 ? wg : wu; out = m == 0 ? wg_t : wu_t;
    Kd = 2048; Nd = 8192;
  } else {
    lt = t - 12288; in = wd; out = wd_t; Kd = 8192; Nd = 2048;
  }
  const int ntx = Nd >> 6;
  const int n0 = (lt % ntx) * 64, k0 = (lt / ntx) * 64;
  const int r = tid >> 4, c4 = (tid & 15) * 4;
#pragma unroll
  for (int rr = 0; rr < 4; ++rr) {
    int kr = rr * 16 + r;
    float4 v = *(const float4*)&in[(size_t)(k0 + kr) * Nd + n0 + c4];
    tile[kr][c4 + 0] = v.x; tile[kr][c4 + 1] = v.y;
    tile[kr][c4 + 2] = v.z; tile[kr][c4 + 3] = v.w;
  }
  __syncthreads();
#pragma unroll
  for (int rr = 0; rr < 4; ++rr) {
    int nr = rr * 16 + r;
    uint2 o;
    o.x = (unsigned)f2bf(tile[c4 + 0][nr]) | ((unsigned)f2bf(tile[c4 + 1][nr]) << 16);
    o.y = (unsigned)f2bf(tile[c4 + 2][nr]) | ((unsigned)f2bf(tile[c4 + 3][nr]) << 16);
    *(uint2*)&out[(size_t)(n0 + nr) * Kd + k0 + c4] = o;
  }
}

// ---------------- staging: RN rows x 64 K into region (swizzled source) ----------------
template <int RN>
__device__ __forceinline__ void stage_op(const u16* src, int ldE,
                                         int row0, int ktbyte, u16* slot,
                                         int w, int lane) {
  constexpr int L = RN / 64;
#pragma unroll
  for (int l = 0; l < L; ++l) {
    const int dst = l * 8192 + w * 1024;
    const int dl = dst + lane * 16;
    const int srcb = dl ^ (((dl >> 7) & 7) << 4);
    const int row = srcb >> 7, colb = srcb & 127;
    gload_lds16((const char*)src + (size_t)(row0 + row) * ldE * 2 + ktbyte + colb,
                (char*)slot + dst);
  }
}

// ---------------- fused QKV GEMM: triple-B (BN=64) sharing one A staging ----------------
__global__ __launch_bounds__(512, 1) void gemm_qkv(
    const u16* __restrict__ A, const u16* __restrict__ Bq,
    const u16* __restrict__ Bk, const u16* __restrict__ Bv,
    int M, int N, int K,
    u16* __restrict__ oq, u16* __restrict__ ok, u16* __restrict__ ovt,
    const float* __restrict__ fc, const float* __restrict__ fs) {
  extern __shared__ u16 smem[];
  const int tid = threadIdx.x;
  const int w = tid >> 6, lane = tid & 63;
  const int nwg = gridDim.x, bid = blockIdx.x;
  const int sw = (bid & 7) * (nwg >> 3) + (bid >> 3);
  const int mtiles = M / 256;
  const int m0 = (sw % mtiles) * 256;
  const int n0 = (sw / mtiles) * 64;
  const int wm = w >> 1, wn = w & 1;
  const int KT = K / 64;
  const int ql = lane & 15, qh = (lane >> 4) * 16;
  f32x4 aq[4][2] = {}, ak[4][2] = {}, av[4][2] = {};

  auto stage = [&](int t, int slot) {
    u16* base = smem + slot * QKV_SLOT_U16;
    const int kb = t * 128;
    stage_op<256>(A,  K, m0, kb, base,          w, lane);
    stage_op<64>(Bq, K, n0, kb, base + 16384, w, lane);
    stage_op<64>(Bk, K, n0, kb, base + 20480, w, lane);
    stage_op<64>(Bv, K, n0, kb, base + 24576, w, lane);
  };

  stage(0, 0);
  for (int t = 0; t < KT; ++t) {
    if (t + 1 < KT) {
      stage(t + 1, (t + 1) & 1);
      asm volatile("s_waitcnt vmcnt(7)" ::: "memory");
    } else {
      asm volatile("s_waitcnt vmcnt(0)" ::: "memory");
    }
    __builtin_amdgcn_s_barrier();
    asm volatile("" ::: "memory");

    const u16* sA = smem + (t & 1) * QKV_SLOT_U16;
    const u16* sQ = sA + 16384;
    const u16* sK = sA + 20480;
    const u16* sV = sA + 24576;
#pragma unroll
    for (int kk = 0; kk < 2; ++kk) {
      bf16x8 af[4], bq[2], bk[2], bv[2];
      const int cb = kk * 64 + qh;
#pragma unroll
      for (int i = 0; i < 4; ++i) {
        const int row = wm * 64 + i * 16 + ql;
        af[i] = *(const bf16x8*)((const char*)sA + (((row << 7) + cb) ^ ((row & 7) << 4)));
      }
#pragma unroll
      for (int j = 0; j < 2; ++j) {
        const int row = wn * 32 + j * 16 + ql;
        const int byt = (((row << 7) + cb) ^ ((row & 7) << 4));
        bq[j] = *(const bf16x8*)((const char*)sQ + byt);
        bk[j] = *(const bf16x8*)((const char*)sK + byt);
        bv[j] = *(const bf16x8*)((const char*)sV + byt);
      }
      __builtin_amdgcn_s_setprio(1);
#pragma unroll
      for (int i = 0; i < 4; ++i)
#pragma unroll
        for (int j = 0; j < 2; ++j) {
          aq[i][j] = __builtin_amdgcn_mfma_f32_16x16x32_bf16(af[i], bq[j], aq[i][j], 0, 0, 0);
          ak[i][j] = __builtin_amdgcn_mfma_f32_16x16x32_bf16(af[i], bk[j], ak[i][j], 0, 0, 0);
          av[i][j] = __builtin_amdgcn_mfma_f32_16x16x32_bf16(af[i], bv[j], av[i][j], 0, 0, 0);
        }
      __builtin_amdgcn_s_setprio(0);
    }
    __builtin_amdgcn_s_barrier();
    asm volatile("" ::: "memory");
  }

  const int rbase = (lane >> 4) * 4;
#pragma unroll
  for (int i = 0; i < 4; ++i) {
#pragma unroll
    for (int j = 0; j < 2; ++j) {
      const int grow0 = m0 + wm * 64 + i * 16 + rbase;
      const int c = n0 + wn * 32 + j * 16 + ql;
      const int i2 = (c & 63) >> 1;
      const int odd = c & 1;
      {
        const int b = grow0 >> 11, s4 = grow0 & (S_LEN - 1);
        const int h = c >> 6, dh = c & 63;
        uint2 ov;
        ov.x = (unsigned)f2bf(av[i][j][0]) | ((unsigned)f2bf(av[i][j][1]) << 16);
        ov.y = (unsigned)f2bf(av[i][j][2]) | ((unsigned)f2bf(av[i][j][3]) << 16);
        *(uint2*)&ovt[((((size_t)b * NHEAD + h) * DHEAD + dh) << 11) + s4] = ov;
      }
#pragma unroll
      for (int r = 0; r < 4; ++r) {
        const int grow = grow0 + r;
        const int s4 = grow & (S_LEN - 1);
        const float cs = fc[s4 * 32 + i2], sn = fs[s4 * 32 + i2];
        {
          const float v = aq[i][j][r];
          const float p = __shfl_xor(v, 1);
          const float outv = odd ? (p * sn + v * cs) : (v * cs - p * sn);
          oq[(size_t)grow * D_MODEL + c] = f2bf(outv);
        }
        {
          const float v = ak[i][j][r];
          const float p = __shfl_xor(v, 1);
          const float outv = odd ? (p * sn + v * cs) : (v * cs - p * sn);
          ok[(size_t)grow * D_MODEL + c] = f2bf(outv);
        }
      }
    }
  }
}

// ---------------- fused gate+up GEMM: 4-phase, all stages at P0, single drain at P3 ----------------
__global__ __launch_bounds__(512, 1) void gemm_gu(
    const u16* __restrict__ A, const u16* __restrict__ Bg, const u16* __restrict__ Bu,
    int M, int N, int K, u16* __restrict__ o0) {
  extern __shared__ u16 smem[];
  const int tid = threadIdx.x;
  const int w = tid >> 6, lane = tid & 63;
  const int nwg = gridDim.x, bid = blockIdx.x;
  const int sw = (bid & 7) * (nwg >> 3) + (bid >> 3);
  const int mtiles = M / 256;
  const int m0 = (sw % mtiles) * 256;
  const int n0 = (sw / mtiles) * 128;
  const int wm = w >> 1, wn = w & 1;
  const int KT = K / 64;
  const int ql = lane & 15, qh = (lane >> 4) * 16;
  f32x4 accg[4][4] = {}, accu[4][4] = {};

  int abyt[4][2], bbyt[4][2];
#pragma unroll
  for (int i = 0; i < 4; ++i)
#pragma unroll
    for (int kk = 0; kk < 2; ++kk) {
      const int ra = wm * 64 + i * 16 + ql;
      abyt[i][kk] = ((ra << 7) + kk * 64 + qh) ^ ((ra & 7) << 4);
      const int rb = wn * 64 + i * 16 + ql;
      bbyt[i][kk] = ((rb << 7) + kk * 64 + qh) ^ ((rb & 7) << 4);
    }

  auto stage_all = [&](int t, int slot) {   // A(4) + Bg(2) + Bu(2) = 8 loads
    u16* base = smem + slot * 32768;
    stage_op<256>(A,  K, m0, t * 128, base,         w, lane);
    stage_op<128>(Bg, K, n0, t * 128, base + 16384, w, lane);
    stage_op<128>(Bu, K, n0, t * 128, base + 24576, w, lane);
  };

  stage_all(0, 0);
  asm volatile("s_waitcnt vmcnt(0)" ::: "memory");
  barrier_f();

  for (int t = 0; t < KT; ++t) {
    const bool last = (t == KT - 1);
    const char* sA = (const char*)smem + (t & 1) * 65536;
    const char* sG = sA + 32768;
    const char* sU = sA + 49152;
    bf16x8 af[4], bb[4];
    // ---- P0: af.bg kk0 | issue ALL of tile t+1 ----
#pragma unroll
    for (int i = 0; i < 4; ++i) af[i] = *(const bf16x8*)(sA + abyt[i][0]);
#pragma unroll
    for (int j = 0; j < 4; ++j) bb[j] = *(const bf16x8*)(sG + bbyt[j][0]);
    if (!last) stage_all(t + 1, (t + 1) & 1);
    barrier_f();
    __builtin_amdgcn_s_setprio(1);
#pragma unroll
    for (int i = 0; i < 4; ++i)
#pragma unroll
      for (int j = 0; j < 4; ++j)
        accg[i][j] = __builtin_amdgcn_mfma_f32_16x16x32_bf16(af[i], bb[j], accg[i][j], 0, 0, 0);
    __builtin_amdgcn_s_setprio(0);
    barrier_f();
    // ---- P1: af.bu kk0 ----
#pragma unroll
    for (int j = 0; j < 4; ++j) bb[j] = *(const bf16x8*)(sU + bbyt[j][0]);
    barrier_f();
    __builtin_amdgcn_s_setprio(1);
#pragma unroll
    for (int i = 0; i < 4; ++i)
#pragma unroll
      for (int j = 0; j < 4; ++j)
        accu[i][j] = __builtin_amdgcn_mfma_f32_16x16x32_bf16(af[i], bb[j], accu[i][j], 0, 0, 0);
    __builtin_amdgcn_s_setprio(0);
    barrier_f();
    // ---- P2: af.bg kk1 ----
#pragma unroll
    for (int i = 0; i < 4; ++i) af[i] = *(const bf16x8*)(sA + abyt[i][1]);
#pragma unroll
    for (int j = 0; j < 4; ++j) bb[j] = *(const bf16x8*)(sG + bbyt[j][1]);
    barrier_f();
    __builtin_amdgcn_s_setprio(1);
#pragma unroll
    for (int i = 0; i < 4; ++i)
#pragma unroll
      for (int j = 0; j < 4; ++j)
        accg[i][j] = __builtin_amdgcn_mfma_f32_16x16x32_bf16(af[i], bb[j], accg[i][j], 0, 0, 0);
    __builtin_amdgcn_s_setprio(0);
    barrier_f();
    // ---- P3: af.bu kk1 | single drain (3 phases of cover for tile t+1) ----
#pragma unroll
    for (int j = 0; j < 4; ++j) bb[j] = *(const bf16x8*)(sU + bbyt[j][1]);
    asm volatile("s_waitcnt vmcnt(0)" ::: "memory");
    barrier_f();
    __builtin_amdgcn_s_setprio(1);
#pragma unroll
    for (int i = 0; i < 4; ++i)
#pragma unroll
      for (int j = 0; j < 4; ++j)
        accu[i][j] = __builtin_amdgcn_mfma_f32_16x16x32_bf16(af[i], bb[j], accu[i][j], 0, 0, 0);
    __builtin_amdgcn_s_setprio(0);
    barrier_f();
  }

  const int rbase = (lane >> 4) * 4;
#pragma unroll
  for (int i = 0; i < 4; ++i) {
#pragma unroll
    for (int j = 0; j < 4; ++j) {
      const int grow0 = m0 + wm * 64 + i * 16 + rbase;
      const int gcol = n0 + wn * 64 + j * 16 + ql;
#pragma unroll
      for (int r = 0; r < 4; ++r) {
        const float g = accg[i][j][r];
        const float u = accu[i][j][r];
        const float sg = g / (1.f + __expf(-g));
        o0[(size_t)(grow0 + r) * N + gcol] = f2bf(sg * u);
      }
    }
  }
}

// ---------------- split-K GEMM: ring-2, 256x256, split-K=2, bf16 partials ----------------
__global__ __launch_bounds__(512, 1) void gemm_dn(
    const u16* __restrict__ A, const u16* __restrict__ Bt,
    int M, int N, int Kld, u16* __restrict__ pbuf) {
  extern __shared__ u16 smem[];
  const int tid = threadIdx.x;
  const int w = tid >> 6, lane = tid & 63;
  const int nwg = gridDim.x, bid = blockIdx.x;
  const int sw = (bid & 7) * (nwg >> 3) + (bid >> 3);
  const int mtiles = M / 256;
  const int tilesPerSplit = mtiles * (N / 256);
  const int split = sw / tilesPerSplit;
  const int tt = sw % tilesPerSplit;
  const int m0 = (tt % mtiles) * 256;
  const int n0 = (tt / mtiles) * 256;
  const u16* Ap = A + (size_t)split * (Kld / 2);
  const u16* Bp = Bt + (size_t)split * (Kld / 2);
  u16* op = pbuf + (size_t)split * M * N;
  const int wm = w >> 2, wn = w & 3;
  const int KT = (Kld / 2) / 64;
  const int ql = lane & 15, qh = (lane >> 4) * 16;
  f32x4 acc[8][4] = {};

  auto stage = [&](int t, int slot) {
    u16* base = smem + slot * 32768;
    const int kb = t * 128;
    stage_op<256>(Ap, Kld, m0, kb, base,         w, lane);
    stage_op<256>(Bp, Kld, n0, kb, base + 16384, w, lane);
  };

  stage(0, 0);
  for (int t = 0; t < KT; ++t) {
    if (t + 1 < KT) {
      stage(t + 1, (t + 1) & 1);
      asm volatile("s_waitcnt vmcnt(8)" ::: "memory");
    } else {
      asm volatile("s_waitcnt vmcnt(0)" ::: "memory");
    }
    __builtin_amdgcn_s_barrier();
    asm volatile("" ::: "memory");

    const u16* sA = smem + (t & 1) * 32768;
    const u16* sB = sA + 16384;
#pragma unroll
    for (int kk = 0; kk < 2; ++kk) {
      bf16x8 af[8], bq[4];
      const int cb = kk * 64 + qh;
#pragma unroll
      for (int i = 0; i < 8; ++i) {
        const int row = wm * 128 + i * 16 + ql;
        af[i] = *(const bf16x8*)((const char*)sA + (((row << 7) + cb) ^ ((row & 7) << 4)));
      }
#pragma unroll
      for (int j = 0; j < 4; ++j) {
        const int row = wn * 64 + j * 16 + ql;
        bq[j] = *(const bf16x8*)((const char*)sB + (((row << 7) + cb) ^ ((row & 7) << 4)));
      }
      __builtin_amdgcn_s_setprio(1);
#pragma unroll
      for (int i = 0; i < 8; ++i)
#pragma unroll
        for (int j = 0; j < 4; ++j)
          acc[i][j] = __builtin_amdgcn_mfma_f32_16x16x32_bf16(af[i], bq[j], acc[i][j], 0, 0, 0);
      __builtin_amdgcn_s_setprio(0);
    }
    __builtin_amdgcn_s_barrier();
    asm volatile("" ::: "memory");
  }

  const int rbase = (lane >> 4) * 4;
#pragma unroll
  for (int i = 0; i < 8; ++i) {
#pragma unroll
    for (int j = 0; j < 4; ++j) {
      const int grow0 = m0 + wm * 128 + i * 16 + rbase;
      const int gcol = n0 + wn * 64 + j * 16 + ql;
#pragma unroll
      for (int r = 0; r < 4; ++r)
        op[(size_t)(grow0 + r) * N + gcol] = f2bf(acc[i][j][r]);
    }
  }
}

// ---------------- down combine: out += p0 + p1 (bf16 partials) ----------------
__global__ __launch_bounds__(256) void combine_kernel(
    const u16* __restrict__ p0, const u16* __restrict__ p1, float* __restrict__ out) {
  const size_t idx = ((size_t)blockIdx.x * 256 + threadIdx.x) * 8;
  bf16x8 a = *(const bf16x8*)&p0[idx];
  bf16x8 b = *(const bf16x8*)&p1[idx];
  float4 c0 = *(const float4*)&out[idx];
  float4 c1 = *(const float4*)&out[idx + 4];
  c0.x += bf2f((u16)a[0]) + bf2f((u16)b[0]);
  c0.y += bf2f((u16)a[1]) + bf2f((u16)b[1]);
  c0.z += bf2f((u16)a[2]) + bf2f((u16)b[2]);
  c0.w += bf2f((u16)a[3]) + bf2f((u16)b[3]);
  c1.x += bf2f((u16)a[4]) + bf2f((u16)b[4]);
  c1.y += bf2f((u16)a[5]) + bf2f((u16)b[5]);
  c1.z += bf2f((u16)a[6]) + bf2f((u16)b[6]);
  c1.w += bf2f((u16)a[7]) + bf2f((u16)b[7]);
  *(float4*)&out[idx] = c0;
  *(float4*)&out[idx + 4] = c1;
}

// ---------------- O-proj combine + residual + fused rmsnorm2 ----------------
__global__ __launch_bounds__(256) void combine_o_norm(
    const u16* __restrict__ p0, const u16* __restrict__ p1,
    const float* __restrict__ x, const float* __restrict__ wt,
    float* __restrict__ out, u16* __restrict__ hn) {
  const int row = blockIdx.x;
  const int tid = threadIdx.x;
  const size_t base = (size_t)row * D_MODEL + tid * 8;
  bf16x8 a = *(const bf16x8*)&p0[base];
  bf16x8 b = *(const bf16x8*)&p1[base];
  float4 x0 = *(const float4*)&x[base];
  float4 x1 = *(const float4*)&x[base + 4];
  float c[8];
  c[0] = x0.x + bf2f((u16)a[0]) + bf2f((u16)b[0]);
  c[1] = x0.y + bf2f((u16)a[1]) + bf2f((u16)b[1]);
  c[2] = x0.z + bf2f((u16)a[2]) + bf2f((u16)b[2]);
  c[3] = x0.w + bf2f((u16)a[3]) + bf2f((u16)b[3]);
  c[4] = x1.x + bf2f((u16)a[4]) + bf2f((u16)b[4]);
  c[5] = x1.y + bf2f((u16)a[5]) + bf2f((u16)b[5]);
  c[6] = x1.z + bf2f((u16)a[6]) + bf2f((u16)b[6]);
  c[7] = x1.w + bf2f((u16)a[7]) + bf2f((u16)b[7]);
  float4 o0 = {c[0], c[1], c[2], c[3]};
  float4 o1 = {c[4], c[5], c[6], c[7]};
  *(float4*)&out[base] = o0;
  *(float4*)&out[base + 4] = o1;
  float ss = 0.f;
#pragma unroll
  for (int e = 0; e < 8; ++e) ss += c[e] * c[e];
#pragma unroll
  for (int d = 1; d < 64; d <<= 1) ss += __shfl_xor(ss, d);
  __shared__ float red[4];
  if ((tid & 63) == 0) red[tid >> 6] = ss;
  __syncthreads();
  const float tot = red[0] + red[1] + red[2] + red[3];
  const float rms = rsqrtf(tot * (1.f / (float)D_MODEL) + 1e-6f);
  float4 wa = *(const float4*)&wt[tid * 8];
  float4 wb = *(const float4*)&wt[tid * 8 + 4];
  uint4 o;
  o.x = (unsigned)f2bf(c[0] * rms * wa.x) | ((unsigned)f2bf(c[1] * rms * wa.y) << 16);
  o.y = (unsigned)f2bf(c[2] * rms * wa.z) | ((unsigned)f2bf(c[3] * rms * wa.w) << 16);
  o.z = (unsigned)f2bf(c[4] * rms * wb.x) | ((unsigned)f2bf(c[5] * rms * wb.y) << 16);
  o.w = (unsigned)f2bf(c[6] * rms * wb.z) | ((unsigned)f2bf(c[7] * rms * wb.w) << 16);
  *(uint4*)&hn[base] = o;
}

// ---------------- Flash attention (causal), swapped-QK^T, swizzled, ring-2, defer-max ----------------
__global__ __launch_bounds__(256) void attn_kernel(
    const u16* __restrict__ q, const u16* __restrict__ k,
    const u16* __restrict__ vt, u16* __restrict__ o) {
  __shared__ u16 lKV[2][128 * 64];
  __shared__ u16 lP[4][32 * 64];
  const int tid = threadIdx.x, w = tid >> 6, lane = tid & 63;
  const int ql = lane & 15, qh16 = (lane >> 4) * 16, rbase = (lane >> 4) * 4;
  const int bx = (int)gridDim.x - 1 - (int)blockIdx.x;
  const int bh = blockIdx.y, b = bh >> 5, h = bh & 31;
  const int q0 = bx * 128;
  const int nt = 2 * bx + 2;
  const char* kbase = (const char*)(k + ((size_t)b * S_LEN) * D_MODEL + h * DHEAD);
  const char* vbase = (const char*)(vt + (size_t)bh * DHEAD * S_LEN);

  bf16x8 qf[2][2];
#pragma unroll
  for (int i = 0; i < 2; ++i) {
    const size_t tok = (size_t)b * S_LEN + q0 + w * 32 + i * 16 + ql;
#pragma unroll
    for (int kk = 0; kk < 2; ++kk) {
      bf16x8 v = *(const bf16x8*)&q[tok * D_MODEL + h * DHEAD + kk * 32 + (lane >> 4) * 8];
#pragma unroll
      for (int e = 0; e < 8; ++e) v[e] = (short)f2bf(bf2f((u16)v[e]) * 0.125f);
      qf[i][kk] = v;
    }
  }

  float m[2] = {-1e30f, -1e30f}, l[2] = {0.f, 0.f};
  f32x4 oacc[2][4] = {};

  auto stage = [&](int kt, int slot) {
    const int s0 = kt * 64;
#pragma unroll
    for (int lo = 0; lo < 2; ++lo) {
      const int dst = lo * 4096 + w * 1024;
      const int dl = dst + lane * 16;
      const int srcb = dl ^ (((dl >> 7) & 7) << 4);
      const int row = srcb >> 7, colb = srcb & 127;
      gload_lds16(kbase + (size_t)(s0 + row) * (D_MODEL * 2) + colb,
                  (char*)&lKV[slot][0] + dst);
    }
#pragma unroll
    for (int lo = 0; lo < 2; ++lo) {
      const int dst = lo * 4096 + w * 1024;
      const int dl = dst + lane * 16;
      const int srcb = dl ^ (((dl >> 7) & 7) << 4);
      const int row = srcb >> 7, colb = srcb & 127;
      gload_lds16(vbase + (size_t)row * (S_LEN * 2) + (size_t)s0 * 2 + colb,
                  (char*)&lKV[slot][64 * 64] + dst);
    }
  };

  stage(0, 0);
  for (int kt = 0; kt < nt; ++kt) {
    if (kt + 1 < nt) {
      stage(kt + 1, (kt + 1) & 1);
      asm volatile("s_waitcnt vmcnt(4)" ::: "memory");
    } else {
      asm volatile("s_waitcnt vmcnt(0)" ::: "memory");
    }
    __builtin_amdgcn_s_barrier();
    asm volatile("" ::: "memory");

    const u16* sK = &lKV[kt & 1][0];
    const u16* sV = &lKV[kt & 1][64 * 64];
    const int s0 = kt * 64;

    f32x4 scT[2][4] = {};
#pragma unroll
    for (int kk = 0; kk < 2; ++kk) {
#pragma unroll
      for (int j = 0; j < 4; ++j) {
        const int row = j * 16 + ql;
        bf16x8 kf = *(const bf16x8*)((const char*)sK +
                      (((row << 7) + kk * 64 + qh16) ^ ((row & 7) << 4)));
#pragma unroll
        for (int i = 0; i < 2; ++i)
          scT[i][j] = __builtin_amdgcn_mfma_f32_16x16x32_bf16(kf, qf[i][kk], scT[i][j], 0, 0, 0);
      }
    }
    const bool diag = (s0 + 63 > q0);
#pragma unroll
    for (int i = 0; i < 2; ++i) {
      const int qrow = q0 + w * 32 + i * 16 + ql;
      if (diag) {
#pragma unroll
        for (int j = 0; j < 4; ++j)
#pragma unroll
          for (int r = 0; r < 4; ++r)
            if (s0 + j * 16 + rbase + r > qrow) scT[i][j][r] = -1e30f;
      }
      float mx = scT[i][0][0];
#pragma unroll
      for (int j = 0; j < 4; ++j)
#pragma unroll
        for (int r = 0; r < 4; ++r) mx = fmaxf(mx, scT[i][j][r]);
      mx = fmaxf(mx, __shfl_xor(mx, 16));
      mx = fmaxf(mx, __shfl_xor(mx, 32));
      float alpha = 1.f;
      if (!__all(mx - m[i] <= 8.f)) {
        const float mnew = fmaxf(m[i], mx);
        alpha = __expf(m[i] - mnew);
        m[i] = mnew;
#pragma unroll
        for (int rr = 0; rr < 4; ++rr) {
          const float ar = __shfl(alpha, rbase + rr);
#pragma unroll
          for (int j = 0; j < 4; ++j) oacc[i][j][rr] *= ar;
        }
      }
      float rs = 0.f;
#pragma unroll
      for (int j = 0; j < 4; ++j)
#pragma unroll
        for (int r = 0; r < 4; ++r) {
          const float p = __expf(scT[i][j][r] - m[i]);
          scT[i][j][r] = p;
          rs += p;
        }
      rs += __shfl_xor(rs, 16);
      rs += __shfl_xor(rs, 32);
      l[i] = l[i] * alpha + rs;
      const int prow = i * 16 + ql;
      const int pb = prow << 7;
      const int swz = (prow & 7) << 4;
#pragma unroll
      for (int j = 0; j < 4; ++j) {
#pragma unroll
        for (int rp = 0; rp < 2; ++rp) {
          const int col = j * 16 + rbase + rp * 2;
          unsigned pk = (unsigned)f2bf(scT[i][j][rp * 2]) |
                        ((unsigned)f2bf(scT[i][j][rp * 2 + 1]) << 16);
          *(unsigned*)((char*)lP[w] + ((pb + col * 2) ^ swz)) = pk;
        }
      }
    }
#pragma unroll
    for (int i = 0; i < 2; ++i) {
      const int arow = i * 16 + ql;
#pragma unroll
      for (int kk = 0; kk < 2; ++kk) {
        bf16x8 pa = *(const bf16x8*)((const char*)lP[w] +
                      (((arow << 7) + kk * 64 + qh16) ^ ((arow & 7) << 4)));
#pragma unroll
        for (int j = 0; j < 4; ++j) {
          const int vrow = j * 16 + ql;
          bf16x8 bv = *(const bf16x8*)((const char*)sV +
                        (((vrow << 7) + kk * 64 + qh16) ^ ((vrow & 7) << 4)));
          oacc[i][j] = __builtin_amdgcn_mfma_f32_16x16x32_bf16(pa, bv, oacc[i][j], 0, 0, 0);
        }
      }
    }
    __builtin_amdgcn_s_barrier();
    asm volatile("" ::: "memory");
  }
#pragma unroll
  for (int i = 0; i < 2; ++i) {
#pragma unroll
    for (int rr = 0; rr < 4; ++rr) {
      const float linv = 1.f / __shfl(l[i], rbase + rr);
      const size_t tok = (size_t)b * S_LEN + q0 + w * 32 + i * 16 + rbase + rr;
#pragma unroll
      for (int j = 0; j < 4; ++j)
        o[tok * D_MODEL + h * DHEAD + j * 16 + ql] = f2bf(oacc[i][j][rr] * linv);
    }
  }
}

// ---------------- host ----------------
extern "C" void kernel_launch(void* const* d_in, const int* in_sizes, int n_in,
                              void* d_out, int out_size, void* d_ws, size_t ws_size,
                              hipStream_t stream) {
  (void)in_sizes; (void)n_in; (void)out_size; (void)ws_size;
  const float* x  = (const float*)d_in[0];
  const float* fc = (const float*)d_in[1];
  const float* fs = (const float*)d_in[2];
  const float* wq = (const float*)d_in[4];
  const float* wk = (const float*)d_in[5];
  const float* wv = (const float*)d_in[6];
  const float* wo = (const float*)d_in[7];
  const float* wg = (const float*)d_in[8];
  const float* wu = (const float*)d_in[9];
  const float* wd = (const float*)d_in[10];
  const float* n1 = (const float*)d_in[11];
  const float* n2 = (const float*)d_in[12];
  float* out = (float*)d_out;

  char* ws = (char*)d_ws;
  size_t off = 0;
  auto alloc = [&](size_t bytes) { void* p = ws + off; off += (bytes + 255) & ~(size_t)255; return p; };
  u16* wq_t = (u16*)alloc((size_t)D_MODEL * D_MODEL * 2);
  u16* wk_t = (u16*)alloc((size_t)D_MODEL * D_MODEL * 2);
  u16* wv_t = (u16*)alloc((size_t)D_MODEL * D_MODEL * 2);
  u16* wo_t = (u16*)alloc((size_t)D_MODEL * D_MODEL * 2);
  u16* wg_t = (u16*)alloc((size_t)D_MODEL * FF_DIM * 2);
  u16* wu_t = (u16*)alloc((size_t)D_MODEL * FF_DIM * 2);
  u16* wd_t = (u16*)alloc((size_t)FF_DIM * D_MODEL * 2);
  u16* hn   = (u16*)alloc((size_t)NTOK * D_MODEL * 2);
  u16* qb   = (u16*)alloc((size_t)NTOK * D_MODEL * 2);
  u16* kb   = (u16*)alloc((size_t)NTOK * D_MODEL * 2);
  u16* vtb  = (u16*)alloc((size_t)NTOK * D_MODEL * 2);
  u16* ao   = (u16*)alloc((size_t)NTOK * D_MODEL * 2);
  u16* gt   = (u16*)alloc((size_t)NTOK * FF_DIM * 2);
  u16* pbuf = qb;   // bf16 split-K partials reuse dead qb/kb region

  // weight conversions + rmsnorm1 in one launch (16384 + 4096 blocks)
  wconv_all<<<16384 + NTOK, 256, 0, stream>>>(wq, wk, wv, wo, wg, wu, wd,
                                              wq_t, wk_t, wv_t, wo_t, wg_t, wu_t, wd_t,
                                              x, n1, hn);
  gemm_qkv<<<512, 512, QKV_LDS_BYTES, stream>>>(hn, wq_t, wk_t, wv_t,
                                                NTOK, D_MODEL, D_MODEL,
                                                qb, kb, vtb, fc, fs);
  attn_kernel<<<dim3(16, 64), 256, 0, stream>>>(qb, kb, vtb, ao);
  gemm_dn<<<256, 512, DN_LDS_BYTES, stream>>>(ao, wo_t, NTOK, D_MODEL, D_MODEL, pbuf);
  combine_o_norm<<<NTOK, 256, 0, stream>>>(pbuf, pbuf + (size_t)NTOK * D_MODEL,
                                           x, n2, out, hn);
  gemm_gu<<<1024, 512, GU_LDS_BYTES, stream>>>(hn, wg_t, wu_t, NTOK, FF_DIM, D_MODEL, gt);
  gemm_dn<<<256, 512, DN_LDS_BYTES, stream>>>(gt, wd_t, NTOK, D_MODEL, FF_DIM, pbuf);
  combine_kernel<<<(NTOK * D_MODEL) / (256 * 8), 256, 0, stream>>>(
      pbuf, pbuf + (size_t)NTOK * D_MODEL, out);
}

// Round 18
// 768.221 us; speedup vs baseline: 1.0244x; 1.0163x over previous
//
#include <hip/hip_runtime.h>

typedef unsigned short u16;
typedef __attribute__((ext_vector_type(8))) short bf16x8;
typedef __attribute__((ext_vector_type(4))) float f32x4;

#define S_LEN 2048
#define D_MODEL 2048
#define NHEAD 32
#define DHEAD 64
#define FF_DIM 8192
#define NTOK 4096

#define GU_LDS_BYTES (2 * 65536)              // 128KB
#define DN_LDS_BYTES (2 * 65536)              // 128KB
#define QKV_SLOT_U16 (16384 + 3 * 4096)       // 28672 u16 = 56KB
#define QKV_LDS_BYTES (2 * QKV_SLOT_U16 * 2)  // 112KB

__device__ __forceinline__ u16 f2bf(float f) {
  union { float f; unsigned u; } v; v.f = f;
  unsigned r = v.u + 0x7fffu + ((v.u >> 16) & 1u);
  return (u16)(r >> 16);
}
__device__ __forceinline__ float bf2f(u16 b) {
  union { unsigned u; float f; } v; v.u = ((unsigned)b) << 16;
  return v.f;
}
__device__ __forceinline__ void gload_lds16(const void* g, void* l) {
  __builtin_amdgcn_global_load_lds(
      (const __attribute__((address_space(1))) void*)g,
      (__attribute__((address_space(3))) void*)l, 16, 0, 0);
}
__device__ __forceinline__ void barrier_f() {
  asm volatile("" ::: "memory");
  __builtin_amdgcn_s_barrier();
  asm volatile("" ::: "memory");
}

// ---------------- merged weight convert + rmsnorm1 (1 launch) ----------------
__global__ __launch_bounds__(256) void wconv_all(
    const float* __restrict__ wq, const float* __restrict__ wk,
    const float* __restrict__ wv, const float* __restrict__ wo,
    const float* __restrict__ wg, const float* __restrict__ wu,
    const float* __restrict__ wd,
    u16* wq_t, u16* wk_t, u16* wv_t, u16* wo_t,
    u16* wg_t, u16* wu_t, u16* wd_t,
    const float* __restrict__ x, const float* __restrict__ n1w,
    u16* __restrict__ hn) {
  __shared__ float tile[64][65];
  const int t = blockIdx.x;
  const int tid = threadIdx.x;
  if (t >= 16384) {
    const int row = t - 16384;
    const float* rp = x + (size_t)row * D_MODEL;
    float4 a = *(const float4*)&rp[tid * 8];
    float4 b = *(const float4*)&rp[tid * 8 + 4];
    float ss = a.x*a.x + a.y*a.y + a.z*a.z + a.w*a.w
             + b.x*b.x + b.y*b.y + b.z*b.z + b.w*b.w;
#pragma unroll
    for (int d = 1; d < 64; d <<= 1) ss += __shfl_xor(ss, d);
    if ((tid & 63) == 0) tile[0][tid >> 6] = ss;
    __syncthreads();
    const float tot = tile[0][0] + tile[0][1] + tile[0][2] + tile[0][3];
    const float rms = rsqrtf(tot * (1.f / (float)D_MODEL) + 1e-6f);
    float4 wa = *(const float4*)&n1w[tid * 8];
    float4 wb = *(const float4*)&n1w[tid * 8 + 4];
    uint4 o;
    o.x = (unsigned)f2bf(a.x * rms * wa.x) | ((unsigned)f2bf(a.y * rms * wa.y) << 16);
    o.y = (unsigned)f2bf(a.z * rms * wa.z) | ((unsigned)f2bf(a.w * rms * wa.w) << 16);
    o.z = (unsigned)f2bf(b.x * rms * wb.x) | ((unsigned)f2bf(b.y * rms * wb.y) << 16);
    o.w = (unsigned)f2bf(b.z * rms * wb.z) | ((unsigned)f2bf(b.w * rms * wb.w) << 16);
    *(uint4*)&hn[(size_t)row * D_MODEL + tid * 8] = o;
    return;
  }
  const float* in; u16* out; int Kd, Nd, lt;
  if (t < 4096) {
    const int m = t >> 10; lt = t & 1023;
    in  = m == 0 ? wq   : m == 1 ? wk   : m == 2 ? wv   : wo;
    out = m == 0 ? wq_t : m == 1 ? wk_t : m == 2 ? wv_t : wo_t;
    Kd = 2048; Nd = 2048;
  } else if (t < 12288) {
    const int m = (t - 4096) >> 12; lt = (t - 4096) & 4095;
    in = m == 0 ? wg : wu; out = m == 0 ? wg_t : wu_t;
    Kd = 2048; Nd = 8192;
  } else {
    lt = t - 12288; in = wd; out = wd_t; Kd = 8192; Nd = 2048;
  }
  const int ntx = Nd >> 6;
  const int n0 = (lt % ntx) * 64, k0 = (lt / ntx) * 64;
  const int r = tid >> 4, c4 = (tid & 15) * 4;
#pragma unroll
  for (int rr = 0; rr < 4; ++rr) {
    int kr = rr * 16 + r;
    float4 v = *(const float4*)&in[(size_t)(k0 + kr) * Nd + n0 + c4];
    tile[kr][c4 + 0] = v.x; tile[kr][c4 + 1] = v.y;
    tile[kr][c4 + 2] = v.z; tile[kr][c4 + 3] = v.w;
  }
  __syncthreads();
#pragma unroll
  for (int rr = 0; rr < 4; ++rr) {
    int nr = rr * 16 + r;
    uint2 o;
    o.x = (unsigned)f2bf(tile[c4 + 0][nr]) | ((unsigned)f2bf(tile[c4 + 1][nr]) << 16);
    o.y = (unsigned)f2bf(tile[c4 + 2][nr]) | ((unsigned)f2bf(tile[c4 + 3][nr]) << 16);
    *(uint2*)&out[(size_t)(n0 + nr) * Kd + k0 + c4] = o;
  }
}

// ---------------- staging: RN rows x 64 K into region (swizzled source) ----------------
template <int RN>
__device__ __forceinline__ void stage_op(const u16* src, int ldE,
                                         int row0, int ktbyte, u16* slot,
                                         int w, int lane) {
  constexpr int L = RN / 64;
#pragma unroll
  for (int l = 0; l < L; ++l) {
    const int dst = l * 8192 + w * 1024;
    const int dl = dst + lane * 16;
    const int srcb = dl ^ (((dl >> 7) & 7) << 4);
    const int row = srcb >> 7, colb = srcb & 127;
    gload_lds16((const char*)src + (size_t)(row0 + row) * ldE * 2 + ktbyte + colb,
                (char*)slot + dst);
  }
}

// ---------------- fused QKV GEMM: triple-B (BN=64) sharing one A staging ----------------
__global__ __launch_bounds__(512, 1) void gemm_qkv(
    const u16* __restrict__ A, const u16* __restrict__ Bq,
    const u16* __restrict__ Bk, const u16* __restrict__ Bv,
    int M, int N, int K,
    u16* __restrict__ oq, u16* __restrict__ ok, u16* __restrict__ ovt,
    const float* __restrict__ fc, const float* __restrict__ fs) {
  extern __shared__ u16 smem[];
  const int tid = threadIdx.x;
  const int w = tid >> 6, lane = tid & 63;
  const int nwg = gridDim.x, bid = blockIdx.x;
  const int sw = (bid & 7) * (nwg >> 3) + (bid >> 3);
  const int mtiles = M / 256;
  const int m0 = (sw % mtiles) * 256;
  const int n0 = (sw / mtiles) * 64;
  const int wm = w >> 1, wn = w & 1;
  const int KT = K / 64;
  const int ql = lane & 15, qh = (lane >> 4) * 16;
  f32x4 aq[4][2] = {}, ak[4][2] = {}, av[4][2] = {};

  auto stage = [&](int t, int slot) {
    u16* base = smem + slot * QKV_SLOT_U16;
    const int kb = t * 128;
    stage_op<256>(A,  K, m0, kb, base,          w, lane);
    stage_op<64>(Bq, K, n0, kb, base + 16384, w, lane);
    stage_op<64>(Bk, K, n0, kb, base + 20480, w, lane);
    stage_op<64>(Bv, K, n0, kb, base + 24576, w, lane);
  };

  stage(0, 0);
  for (int t = 0; t < KT; ++t) {
    if (t + 1 < KT) {
      stage(t + 1, (t + 1) & 1);
      asm volatile("s_waitcnt vmcnt(7)" ::: "memory");
    } else {
      asm volatile("s_waitcnt vmcnt(0)" ::: "memory");
    }
    __builtin_amdgcn_s_barrier();
    asm volatile("" ::: "memory");

    const u16* sA = smem + (t & 1) * QKV_SLOT_U16;
    const u16* sQ = sA + 16384;
    const u16* sK = sA + 20480;
    const u16* sV = sA + 24576;
#pragma unroll
    for (int kk = 0; kk < 2; ++kk) {
      bf16x8 af[4], bq[2], bk[2], bv[2];
      const int cb = kk * 64 + qh;
#pragma unroll
      for (int i = 0; i < 4; ++i) {
        const int row = wm * 64 + i * 16 + ql;
        af[i] = *(const bf16x8*)((const char*)sA + (((row << 7) + cb) ^ ((row & 7) << 4)));
      }
#pragma unroll
      for (int j = 0; j < 2; ++j) {
        const int row = wn * 32 + j * 16 + ql;
        const int byt = (((row << 7) + cb) ^ ((row & 7) << 4));
        bq[j] = *(const bf16x8*)((const char*)sQ + byt);
        bk[j] = *(const bf16x8*)((const char*)sK + byt);
        bv[j] = *(const bf16x8*)((const char*)sV + byt);
      }
      __builtin_amdgcn_s_setprio(1);
#pragma unroll
      for (int i = 0; i < 4; ++i)
#pragma unroll
        for (int j = 0; j < 2; ++j) {
          aq[i][j] = __builtin_amdgcn_mfma_f32_16x16x32_bf16(af[i], bq[j], aq[i][j], 0, 0, 0);
          ak[i][j] = __builtin_amdgcn_mfma_f32_16x16x32_bf16(af[i], bk[j], ak[i][j], 0, 0, 0);
          av[i][j] = __builtin_amdgcn_mfma_f32_16x16x32_bf16(af[i], bv[j], av[i][j], 0, 0, 0);
        }
      __builtin_amdgcn_s_setprio(0);
    }
    __builtin_amdgcn_s_barrier();
    asm volatile("" ::: "memory");
  }

  const int rbase = (lane >> 4) * 4;
#pragma unroll
  for (int i = 0; i < 4; ++i) {
#pragma unroll
    for (int j = 0; j < 2; ++j) {
      const int grow0 = m0 + wm * 64 + i * 16 + rbase;
      const int c = n0 + wn * 32 + j * 16 + ql;
      const int i2 = (c & 63) >> 1;
      const int odd = c & 1;
      {
        const int b = grow0 >> 11, s4 = grow0 & (S_LEN - 1);
        const int h = c >> 6, dh = c & 63;
        uint2 ov;
        ov.x = (unsigned)f2bf(av[i][j][0]) | ((unsigned)f2bf(av[i][j][1]) << 16);
        ov.y = (unsigned)f2bf(av[i][j][2]) | ((unsigned)f2bf(av[i][j][3]) << 16);
        *(uint2*)&ovt[((((size_t)b * NHEAD + h) * DHEAD + dh) << 11) + s4] = ov;
      }
#pragma unroll
      for (int r = 0; r < 4; ++r) {
        const int grow = grow0 + r;
        const int s4 = grow & (S_LEN - 1);
        const float cs = fc[s4 * 32 + i2], sn = fs[s4 * 32 + i2];
        {
          const float v = aq[i][j][r];
          const float p = __shfl_xor(v, 1);
          const float outv = odd ? (p * sn + v * cs) : (v * cs - p * sn);
          oq[(size_t)grow * D_MODEL + c] = f2bf(outv);
        }
        {
          const float v = ak[i][j][r];
          const float p = __shfl_xor(v, 1);
          const float outv = odd ? (p * sn + v * cs) : (v * cs - p * sn);
          ok[(size_t)grow * D_MODEL + c] = f2bf(outv);
        }
      }
    }
  }
}

// ---------------- fused gate+up GEMM: 4-phase pipelined (R15 schedule), ring-2 ----------------
__global__ __launch_bounds__(512, 1) void gemm_gu(
    const u16* __restrict__ A, const u16* __restrict__ Bg, const u16* __restrict__ Bu,
    int M, int N, int K, u16* __restrict__ o0) {
  extern __shared__ u16 smem[];
  const int tid = threadIdx.x;
  const int w = tid >> 6, lane = tid & 63;
  const int nwg = gridDim.x, bid = blockIdx.x;
  const int sw = (bid & 7) * (nwg >> 3) + (bid >> 3);
  const int mtiles = M / 256;
  const int m0 = (sw % mtiles) * 256;
  const int n0 = (sw / mtiles) * 128;
  const int wm = w >> 1, wn = w & 1;
  const int KT = K / 64;
  const int ql = lane & 15, qh = (lane >> 4) * 16;
  f32x4 accg[4][4] = {}, accu[4][4] = {};

  int abyt[4][2], bbyt[4][2];
#pragma unroll
  for (int i = 0; i < 4; ++i)
#pragma unroll
    for (int kk = 0; kk < 2; ++kk) {
      const int ra = wm * 64 + i * 16 + ql;
      abyt[i][kk] = ((ra << 7) + kk * 64 + qh) ^ ((ra & 7) << 4);
      const int rb = wn * 64 + i * 16 + ql;
      bbyt[i][kk] = ((rb << 7) + kk * 64 + qh) ^ ((rb & 7) << 4);
    }

  auto stage_E = [&](int t, int slot) {
    u16* base = smem + slot * 32768;
    stage_op<256>(A,  K, m0, t * 128, base,         w, lane);
    stage_op<128>(Bg, K, n0, t * 128, base + 16384, w, lane);
  };
  auto stage_L = [&](int t, int slot) {
    u16* base = smem + slot * 32768;
    stage_op<128>(Bu, K, n0, t * 128, base + 24576, w, lane);
  };

  stage_E(0, 0);
  stage_L(0, 0);
  asm volatile("s_waitcnt vmcnt(2)" ::: "memory");
  barrier_f();

  for (int t = 0; t < KT; ++t) {
    const bool last = (t == KT - 1);
    const char* sA = (const char*)smem + (t & 1) * 65536;
    const char* sG = sA + 32768;
    const char* sU = sA + 49152;
    bf16x8 af[4], bb[4];
#pragma unroll
    for (int i = 0; i < 4; ++i) af[i] = *(const bf16x8*)(sA + abyt[i][0]);
#pragma unroll
    for (int j = 0; j < 4; ++j) bb[j] = *(const bf16x8*)(sG + bbyt[j][0]);
    if (!last) {
      stage_E(t + 1, (t + 1) & 1);
      asm volatile("s_waitcnt vmcnt(6)" ::: "memory");
    } else {
      asm volatile("s_waitcnt vmcnt(0)" ::: "memory");
    }
    barrier_f();
    __builtin_amdgcn_s_setprio(1);
#pragma unroll
    for (int i = 0; i < 4; ++i)
#pragma unroll
      for (int j = 0; j < 4; ++j)
        accg[i][j] = __builtin_amdgcn_mfma_f32_16x16x32_bf16(af[i], bb[j], accg[i][j], 0, 0, 0);
    __builtin_amdgcn_s_setprio(0);
    barrier_f();
#pragma unroll
    for (int j = 0; j < 4; ++j) bb[j] = *(const bf16x8*)(sU + bbyt[j][0]);
    if (!last) stage_L(t + 1, (t + 1) & 1);
    barrier_f();
    __builtin_amdgcn_s_setprio(1);
#pragma unroll
    for (int i = 0; i < 4; ++i)
#pragma unroll
      for (int j = 0; j < 4; ++j)
        accu[i][j] = __builtin_amdgcn_mfma_f32_16x16x32_bf16(af[i], bb[j], accu[i][j], 0, 0, 0);
    __builtin_amdgcn_s_setprio(0);
    barrier_f();
#pragma unroll
    for (int i = 0; i < 4; ++i) af[i] = *(const bf16x8*)(sA + abyt[i][1]);
#pragma unroll
    for (int j = 0; j < 4; ++j) bb[j] = *(const bf16x8*)(sG + bbyt[j][1]);
    barrier_f();
    __builtin_amdgcn_s_setprio(1);
#pragma unroll
    for (int i = 0; i < 4; ++i)
#pragma unroll
      for (int j = 0; j < 4; ++j)
        accg[i][j] = __builtin_amdgcn_mfma_f32_16x16x32_bf16(af[i], bb[j], accg[i][j], 0, 0, 0);
    __builtin_amdgcn_s_setprio(0);
    barrier_f();
#pragma unroll
    for (int j = 0; j < 4; ++j) bb[j] = *(const bf16x8*)(sU + bbyt[j][1]);
    if (!last) asm volatile("s_waitcnt vmcnt(2)" ::: "memory");
    barrier_f();
    __builtin_amdgcn_s_setprio(1);
#pragma unroll
    for (int i = 0; i < 4; ++i)
#pragma unroll
      for (int j = 0; j < 4; ++j)
        accu[i][j] = __builtin_amdgcn_mfma_f32_16x16x32_bf16(af[i], bb[j], accu[i][j], 0, 0, 0);
    __builtin_amdgcn_s_setprio(0);
    barrier_f();
  }

  const int rbase = (lane >> 4) * 4;
#pragma unroll
  for (int i = 0; i < 4; ++i) {
#pragma unroll
    for (int j = 0; j < 4; ++j) {
      const int grow0 = m0 + wm * 64 + i * 16 + rbase;
      const int gcol = n0 + wn * 64 + j * 16 + ql;
#pragma unroll
      for (int r = 0; r < 4; ++r) {
        const float g = accg[i][j][r];
        const float u = accu[i][j][r];
        const float sg = g / (1.f + __expf(-g));
        o0[(size_t)(grow0 + r) * N + gcol] = f2bf(sg * u);
      }
    }
  }
}

// ---------------- split-K GEMM: ring-2, 256x256, split-K=2, bf16 partials ----------------
__global__ __launch_bounds__(512, 1) void gemm_dn(
    const u16* __restrict__ A, const u16* __restrict__ Bt,
    int M, int N, int Kld, u16* __restrict__ pbuf) {
  extern __shared__ u16 smem[];
  const int tid = threadIdx.x;
  const int w = tid >> 6, lane = tid & 63;
  const int nwg = gridDim.x, bid = blockIdx.x;
  const int sw = (bid & 7) * (nwg >> 3) + (bid >> 3);
  const int mtiles = M / 256;
  const int tilesPerSplit = mtiles * (N / 256);
  const int split = sw / tilesPerSplit;
  const int tt = sw % tilesPerSplit;
  const int m0 = (tt % mtiles) * 256;
  const int n0 = (tt / mtiles) * 256;
  const u16* Ap = A + (size_t)split * (Kld / 2);
  const u16* Bp = Bt + (size_t)split * (Kld / 2);
  u16* op = pbuf + (size_t)split * M * N;
  const int wm = w >> 2, wn = w & 3;
  const int KT = (Kld / 2) / 64;
  const int ql = lane & 15, qh = (lane >> 4) * 16;
  f32x4 acc[8][4] = {};

  auto stage = [&](int t, int slot) {
    u16* base = smem + slot * 32768;
    const int kb = t * 128;
    stage_op<256>(Ap, Kld, m0, kb, base,         w, lane);
    stage_op<256>(Bp, Kld, n0, kb, base + 16384, w, lane);
  };

  stage(0, 0);
  for (int t = 0; t < KT; ++t) {
    if (t + 1 < KT) {
      stage(t + 1, (t + 1) & 1);
      asm volatile("s_waitcnt vmcnt(8)" ::: "memory");
    } else {
      asm volatile("s_waitcnt vmcnt(0)" ::: "memory");
    }
    __builtin_amdgcn_s_barrier();
    asm volatile("" ::: "memory");

    const u16* sA = smem + (t & 1) * 32768;
    const u16* sB = sA + 16384;
#pragma unroll
    for (int kk = 0; kk < 2; ++kk) {
      bf16x8 af[8], bq[4];
      const int cb = kk * 64 + qh;
#pragma unroll
      for (int i = 0; i < 8; ++i) {
        const int row = wm * 128 + i * 16 + ql;
        af[i] = *(const bf16x8*)((const char*)sA + (((row << 7) + cb) ^ ((row & 7) << 4)));
      }
#pragma unroll
      for (int j = 0; j < 4; ++j) {
        const int row = wn * 64 + j * 16 + ql;
        bq[j] = *(const bf16x8*)((const char*)sB + (((row << 7) + cb) ^ ((row & 7) << 4)));
      }
      __builtin_amdgcn_s_setprio(1);
#pragma unroll
      for (int i = 0; i < 8; ++i)
#pragma unroll
        for (int j = 0; j < 4; ++j)
          acc[i][j] = __builtin_amdgcn_mfma_f32_16x16x32_bf16(af[i], bq[j], acc[i][j], 0, 0, 0);
      __builtin_amdgcn_s_setprio(0);
    }
    __builtin_amdgcn_s_barrier();
    asm volatile("" ::: "memory");
  }

  const int rbase = (lane >> 4) * 4;
#pragma unroll
  for (int i = 0; i < 8; ++i) {
#pragma unroll
    for (int j = 0; j < 4; ++j) {
      const int grow0 = m0 + wm * 128 + i * 16 + rbase;
      const int gcol = n0 + wn * 64 + j * 16 + ql;
#pragma unroll
      for (int r = 0; r < 4; ++r)
        op[(size_t)(grow0 + r) * N + gcol] = f2bf(acc[i][j][r]);
    }
  }
}

// ---------------- down combine: out += p0 + p1 (bf16 partials) ----------------
__global__ __launch_bounds__(256) void combine_kernel(
    const u16* __restrict__ p0, const u16* __restrict__ p1, float* __restrict__ out) {
  const size_t idx = ((size_t)blockIdx.x * 256 + threadIdx.x) * 8;
  bf16x8 a = *(const bf16x8*)&p0[idx];
  bf16x8 b = *(const bf16x8*)&p1[idx];
  float4 c0 = *(const float4*)&out[idx];
  float4 c1 = *(const float4*)&out[idx + 4];
  c0.x += bf2f((u16)a[0]) + bf2f((u16)b[0]);
  c0.y += bf2f((u16)a[1]) + bf2f((u16)b[1]);
  c0.z += bf2f((u16)a[2]) + bf2f((u16)b[2]);
  c0.w += bf2f((u16)a[3]) + bf2f((u16)b[3]);
  c1.x += bf2f((u16)a[4]) + bf2f((u16)b[4]);
  c1.y += bf2f((u16)a[5]) + bf2f((u16)b[5]);
  c1.z += bf2f((u16)a[6]) + bf2f((u16)b[6]);
  c1.w += bf2f((u16)a[7]) + bf2f((u16)b[7]);
  *(float4*)&out[idx] = c0;
  *(float4*)&out[idx + 4] = c1;
}

// ---------------- O-proj combine + residual + fused rmsnorm2 ----------------
__global__ __launch_bounds__(256) void combine_o_norm(
    const u16* __restrict__ p0, const u16* __restrict__ p1,
    const float* __restrict__ x, const float* __restrict__ wt,
    float* __restrict__ out, u16* __restrict__ hn) {
  const int row = blockIdx.x;
  const int tid = threadIdx.x;
  const size_t base = (size_t)row * D_MODEL + tid * 8;
  bf16x8 a = *(const bf16x8*)&p0[base];
  bf16x8 b = *(const bf16x8*)&p1[base];
  float4 x0 = *(const float4*)&x[base];
  float4 x1 = *(const float4*)&x[base + 4];
  float c[8];
  c[0] = x0.x + bf2f((u16)a[0]) + bf2f((u16)b[0]);
  c[1] = x0.y + bf2f((u16)a[1]) + bf2f((u16)b[1]);
  c[2] = x0.z + bf2f((u16)a[2]) + bf2f((u16)b[2]);
  c[3] = x0.w + bf2f((u16)a[3]) + bf2f((u16)b[3]);
  c[4] = x1.x + bf2f((u16)a[4]) + bf2f((u16)b[4]);
  c[5] = x1.y + bf2f((u16)a[5]) + bf2f((u16)b[5]);
  c[6] = x1.z + bf2f((u16)a[6]) + bf2f((u16)b[6]);
  c[7] = x1.w + bf2f((u16)a[7]) + bf2f((u16)b[7]);
  float4 o0 = {c[0], c[1], c[2], c[3]};
  float4 o1 = {c[4], c[5], c[6], c[7]};
  *(float4*)&out[base] = o0;
  *(float4*)&out[base + 4] = o1;
  float ss = 0.f;
#pragma unroll
  for (int e = 0; e < 8; ++e) ss += c[e] * c[e];
#pragma unroll
  for (int d = 1; d < 64; d <<= 1) ss += __shfl_xor(ss, d);
  __shared__ float red[4];
  if ((tid & 63) == 0) red[tid >> 6] = ss;
  __syncthreads();
  const float tot = red[0] + red[1] + red[2] + red[3];
  const float rms = rsqrtf(tot * (1.f / (float)D_MODEL) + 1e-6f);
  float4 wa = *(const float4*)&wt[tid * 8];
  float4 wb = *(const float4*)&wt[tid * 8 + 4];
  uint4 o;
  o.x = (unsigned)f2bf(c[0] * rms * wa.x) | ((unsigned)f2bf(c[1] * rms * wa.y) << 16);
  o.y = (unsigned)f2bf(c[2] * rms * wa.z) | ((unsigned)f2bf(c[3] * rms * wa.w) << 16);
  o.z = (unsigned)f2bf(c[4] * rms * wb.x) | ((unsigned)f2bf(c[5] * rms * wb.y) << 16);
  o.w = (unsigned)f2bf(c[6] * rms * wb.z) | ((unsigned)f2bf(c[7] * rms * wb.w) << 16);
  *(uint4*)&hn[base] = o;
}

// ---------------- Flash attention (causal), swapped-QK^T, swizzled, ring-2, defer-max ----------------
__global__ __launch_bounds__(256) void attn_kernel(
    const u16* __restrict__ q, const u16* __restrict__ k,
    const u16* __restrict__ vt, u16* __restrict__ o) {
  __shared__ u16 lKV[2][128 * 64];
  __shared__ u16 lP[4][32 * 64];
  const int tid = threadIdx.x, w = tid >> 6, lane = tid & 63;
  const int ql = lane & 15, qh16 = (lane >> 4) * 16, rbase = (lane >> 4) * 4;
  const int bx = (int)gridDim.x - 1 - (int)blockIdx.x;
  const int bh = blockIdx.y, b = bh >> 5, h = bh & 31;
  const int q0 = bx * 128;
  const int nt = 2 * bx + 2;
  const char* kbase = (const char*)(k + ((size_t)b * S_LEN) * D_MODEL + h * DHEAD);
  const char* vbase = (const char*)(vt + (size_t)bh * DHEAD * S_LEN);

  bf16x8 qf[2][2];
#pragma unroll
  for (int i = 0; i < 2; ++i) {
    const size_t tok = (size_t)b * S_LEN + q0 + w * 32 + i * 16 + ql;
#pragma unroll
    for (int kk = 0; kk < 2; ++kk) {
      bf16x8 v = *(const bf16x8*)&q[tok * D_MODEL + h * DHEAD + kk * 32 + (lane >> 4) * 8];
#pragma unroll
      for (int e = 0; e < 8; ++e) v[e] = (short)f2bf(bf2f((u16)v[e]) * 0.125f);
      qf[i][kk] = v;
    }
  }

  float m[2] = {-1e30f, -1e30f}, l[2] = {0.f, 0.f};
  f32x4 oacc[2][4] = {};

  auto stage = [&](int kt, int slot) {
    const int s0 = kt * 64;
#pragma unroll
    for (int lo = 0; lo < 2; ++lo) {
      const int dst = lo * 4096 + w * 1024;
      const int dl = dst + lane * 16;
      const int srcb = dl ^ (((dl >> 7) & 7) << 4);
      const int row = srcb >> 7, colb = srcb & 127;
      gload_lds16(kbase + (size_t)(s0 + row) * (D_MODEL * 2) + colb,
                  (char*)&lKV[slot][0] + dst);
    }
#pragma unroll
    for (int lo = 0; lo < 2; ++lo) {
      const int dst = lo * 4096 + w * 1024;
      const int dl = dst + lane * 16;
      const int srcb = dl ^ (((dl >> 7) & 7) << 4);
      const int row = srcb >> 7, colb = srcb & 127;
      gload_lds16(vbase + (size_t)row * (S_LEN * 2) + (size_t)s0 * 2 + colb,
                  (char*)&lKV[slot][64 * 64] + dst);
    }
  };

  stage(0, 0);
  for (int kt = 0; kt < nt; ++kt) {
    if (kt + 1 < nt) {
      stage(kt + 1, (kt + 1) & 1);
      asm volatile("s_waitcnt vmcnt(4)" ::: "memory");
    } else {
      asm volatile("s_waitcnt vmcnt(0)" ::: "memory");
    }
    __builtin_amdgcn_s_barrier();
    asm volatile("" ::: "memory");

    const u16* sK = &lKV[kt & 1][0];
    const u16* sV = &lKV[kt & 1][64 * 64];
    const int s0 = kt * 64;

    f32x4 scT[2][4] = {};
#pragma unroll
    for (int kk = 0; kk < 2; ++kk) {
#pragma unroll
      for (int j = 0; j < 4; ++j) {
        const int row = j * 16 + ql;
        bf16x8 kf = *(const bf16x8*)((const char*)sK +
                      (((row << 7) + kk * 64 + qh16) ^ ((row & 7) << 4)));
#pragma unroll
        for (int i = 0; i < 2; ++i)
          scT[i][j] = __builtin_amdgcn_mfma_f32_16x16x32_bf16(kf, qf[i][kk], scT[i][j], 0, 0, 0);
      }
    }
    const bool diag = (s0 + 63 > q0);
#pragma unroll
    for (int i = 0; i < 2; ++i) {
      const int qrow = q0 + w * 32 + i * 16 + ql;
      if (diag) {
#pragma unroll
        for (int j = 0; j < 4; ++j)
#pragma unroll
          for (int r = 0; r < 4; ++r)
            if (s0 + j * 16 + rbase + r > qrow) scT[i][j][r] = -1e30f;
      }
      float mx = scT[i][0][0];
#pragma unroll
      for (int j = 0; j < 4; ++j)
#pragma unroll
        for (int r = 0; r < 4; ++r) mx = fmaxf(mx, scT[i][j][r]);
      mx = fmaxf(mx, __shfl_xor(mx, 16));
      mx = fmaxf(mx, __shfl_xor(mx, 32));
      float alpha = 1.f;
      if (!__all(mx - m[i] <= 8.f)) {
        const float mnew = fmaxf(m[i], mx);
        alpha = __expf(m[i] - mnew);
        m[i] = mnew;
#pragma unroll
        for (int rr = 0; rr < 4; ++rr) {
          const float ar = __shfl(alpha, rbase + rr);
#pragma unroll
          for (int j = 0; j < 4; ++j) oacc[i][j][rr] *= ar;
        }
      }
      float rs = 0.f;
#pragma unroll
      for (int j = 0; j < 4; ++j)
#pragma unroll
        for (int r = 0; r < 4; ++r) {
          const float p = __expf(scT[i][j][r] - m[i]);
          scT[i][j][r] = p;
          rs += p;
        }
      rs += __shfl_xor(rs, 16);
      rs += __shfl_xor(rs, 32);
      l[i] = l[i] * alpha + rs;
      const int prow = i * 16 + ql;
      const int pb = prow << 7;
      const int swz = (prow & 7) << 4;
#pragma unroll
      for (int j = 0; j < 4; ++j) {
#pragma unroll
        for (int rp = 0; rp < 2; ++rp) {
          const int col = j * 16 + rbase + rp * 2;
          unsigned pk = (unsigned)f2bf(scT[i][j][rp * 2]) |
                        ((unsigned)f2bf(scT[i][j][rp * 2 + 1]) << 16);
          *(unsigned*)((char*)lP[w] + ((pb + col * 2) ^ swz)) = pk;
        }
      }
    }
#pragma unroll
    for (int i = 0; i < 2; ++i) {
      const int arow = i * 16 + ql;
#pragma unroll
      for (int kk = 0; kk < 2; ++kk) {
        bf16x8 pa = *(const bf16x8*)((const char*)lP[w] +
                      (((arow << 7) + kk * 64 + qh16) ^ ((arow & 7) << 4)));
#pragma unroll
        for (int j = 0; j < 4; ++j) {
          const int vrow = j * 16 + ql;
          bf16x8 bv = *(const bf16x8*)((const char*)sV +
                        (((vrow << 7) + kk * 64 + qh16) ^ ((vrow & 7) << 4)));
          oacc[i][j] = __builtin_amdgcn_mfma_f32_16x16x32_bf16(pa, bv, oacc[i][j], 0, 0, 0);
        }
      }
    }
    __builtin_amdgcn_s_barrier();
    asm volatile("" ::: "memory");
  }
#pragma unroll
  for (int i = 0; i < 2; ++i) {
#pragma unroll
    for (int rr = 0; rr < 4; ++rr) {
      const float linv = 1.f / __shfl(l[i], rbase + rr);
      const size_t tok = (size_t)b * S_LEN + q0 + w * 32 + i * 16 + rbase + rr;
#pragma unroll
      for (int j = 0; j < 4; ++j)
        o[tok * D_MODEL + h * DHEAD + j * 16 + ql] = f2bf(oacc[i][j][rr] * linv);
    }
  }
}

// ---------------- host ----------------
extern "C" void kernel_launch(void* const* d_in, const int* in_sizes, int n_in,
                              void* d_out, int out_size, void* d_ws, size_t ws_size,
                              hipStream_t stream) {
  (void)in_sizes; (void)n_in; (void)out_size; (void)ws_size;
  const float* x  = (const float*)d_in[0];
  const float* fc = (const float*)d_in[1];
  const float* fs = (const float*)d_in[2];
  const float* wq = (const float*)d_in[4];
  const float* wk = (const float*)d_in[5];
  const float* wv = (const float*)d_in[6];
  const float* wo = (const float*)d_in[7];
  const float* wg = (const float*)d_in[8];
  const float* wu = (const float*)d_in[9];
  const float* wd = (const float*)d_in[10];
  const float* n1 = (const float*)d_in[11];
  const float* n2 = (const float*)d_in[12];
  float* out = (float*)d_out;

  char* ws = (char*)d_ws;
  size_t off = 0;
  auto alloc = [&](size_t bytes) { void* p = ws + off; off += (bytes + 255) & ~(size_t)255; return p; };
  u16* wq_t = (u16*)alloc((size_t)D_MODEL * D_MODEL * 2);
  u16* wk_t = (u16*)alloc((size_t)D_MODEL * D_MODEL * 2);
  u16* wv_t = (u16*)alloc((size_t)D_MODEL * D_MODEL * 2);
  u16* wo_t = (u16*)alloc((size_t)D_MODEL * D_MODEL * 2);
  u16* wg_t = (u16*)alloc((size_t)D_MODEL * FF_DIM * 2);
  u16* wu_t = (u16*)alloc((size_t)D_MODEL * FF_DIM * 2);
  u16* wd_t = (u16*)alloc((size_t)FF_DIM * D_MODEL * 2);
  u16* hn   = (u16*)alloc((size_t)NTOK * D_MODEL * 2);
  u16* qb   = (u16*)alloc((size_t)NTOK * D_MODEL * 2);
  u16* kb   = (u16*)alloc((size_t)NTOK * D_MODEL * 2);
  u16* vtb  = (u16*)alloc((size_t)NTOK * D_MODEL * 2);
  u16* ao   = (u16*)alloc((size_t)NTOK * D_MODEL * 2);
  u16* gt   = (u16*)alloc((size_t)NTOK * FF_DIM * 2);
  u16* pbuf = qb;   // bf16 split-K partials reuse dead qb/kb region

  wconv_all<<<16384 + NTOK, 256, 0, stream>>>(wq, wk, wv, wo, wg, wu, wd,
                                              wq_t, wk_t, wv_t, wo_t, wg_t, wu_t, wd_t,
                                              x, n1, hn);
  gemm_qkv<<<512, 512, QKV_LDS_BYTES, stream>>>(hn, wq_t, wk_t, wv_t,
                                                NTOK, D_MODEL, D_MODEL,
                                                qb, kb, vtb, fc, fs);
  attn_kernel<<<dim3(16, 64), 256, 0, stream>>>(qb, kb, vtb, ao);
  gemm_dn<<<256, 512, DN_LDS_BYTES, stream>>>(ao, wo_t, NTOK, D_MODEL, D_MODEL, pbuf);
  combine_o_norm<<<NTOK, 256, 0, stream>>>(pbuf, pbuf + (size_t)NTOK * D_MODEL,
                                           x, n2, out, hn);
  gemm_gu<<<1024, 512, GU_LDS_BYTES, stream>>>(hn, wg_t, wu_t, NTOK, FF_DIM, D_MODEL, gt);
  gemm_dn<<<256, 512, DN_LDS_BYTES, stream>>>(gt, wd_t, NTOK, D_MODEL, FF_DIM, pbuf);
  combine_kernel<<<(NTOK * D_MODEL) / (256 * 8), 256, 0, stream>>>(
      pbuf, pbuf + (size_t)NTOK * D_MODEL, out);
}

// Round 19
// 759.410 us; speedup vs baseline: 1.0363x; 1.0116x over previous
//
#include <hip/hip_runtime.h>

typedef unsigned short u16;
typedef __attribute__((ext_vector_type(8))) short bf16x8;
typedef __attribute__((ext_vector_type(4))) float f32x4;

#define S_LEN 2048
#define D_MODEL 2048
#define NHEAD 32
#define DHEAD 64
#define FF_DIM 8192
#define NTOK 4096

#define GU_LDS_BYTES (2 * 65536)              // 128KB
#define DN_LDS_BYTES (2 * 65536)              // 128KB
#define QKV_SLOT_U16 (16384 + 3 * 4096)       // 28672 u16 = 56KB
#define QKV_LDS_BYTES (2 * QKV_SLOT_U16 * 2)  // 112KB

__device__ __forceinline__ u16 f2bf(float f) {
  union { float f; unsigned u; } v; v.f = f;
  unsigned r = v.u + 0x7fffu + ((v.u >> 16) & 1u);
  return (u16)(r >> 16);
}
__device__ __forceinline__ float bf2f(u16 b) {
  union { unsigned u; float f; } v; v.u = ((unsigned)b) << 16;
  return v.f;
}
__device__ __forceinline__ void gload_lds16(const void* g, void* l) {
  __builtin_amdgcn_global_load_lds(
      (const __attribute__((address_space(1))) void*)g,
      (__attribute__((address_space(3))) void*)l, 16, 0, 0);
}
__device__ __forceinline__ void barrier_f() {
  asm volatile("" ::: "memory");
  __builtin_amdgcn_s_barrier();
  asm volatile("" ::: "memory");
}

// ---------------- merged weight convert + rmsnorm1 (1 launch) ----------------
__global__ __launch_bounds__(256) void wconv_all(
    const float* __restrict__ wq, const float* __restrict__ wk,
    const float* __restrict__ wv, const float* __restrict__ wo,
    const float* __restrict__ wg, const float* __restrict__ wu,
    const float* __restrict__ wd,
    u16* wq_t, u16* wk_t, u16* wv_t, u16* wo_t,
    u16* wg_t, u16* wu_t, u16* wd_t,
    const float* __restrict__ x, const float* __restrict__ n1w,
    u16* __restrict__ hn) {
  __shared__ float tile[64][65];
  const int t = blockIdx.x;
  const int tid = threadIdx.x;
  if (t >= 16384) {
    const int row = t - 16384;
    const float* rp = x + (size_t)row * D_MODEL;
    float4 a = *(const float4*)&rp[tid * 8];
    float4 b = *(const float4*)&rp[tid * 8 + 4];
    float ss = a.x*a.x + a.y*a.y + a.z*a.z + a.w*a.w
             + b.x*b.x + b.y*b.y + b.z*b.z + b.w*b.w;
#pragma unroll
    for (int d = 1; d < 64; d <<= 1) ss += __shfl_xor(ss, d);
    if ((tid & 63) == 0) tile[0][tid >> 6] = ss;
    __syncthreads();
    const float tot = tile[0][0] + tile[0][1] + tile[0][2] + tile[0][3];
    const float rms = rsqrtf(tot * (1.f / (float)D_MODEL) + 1e-6f);
    float4 wa = *(const float4*)&n1w[tid * 8];
    float4 wb = *(const float4*)&n1w[tid * 8 + 4];
    uint4 o;
    o.x = (unsigned)f2bf(a.x * rms * wa.x) | ((unsigned)f2bf(a.y * rms * wa.y) << 16);
    o.y = (unsigned)f2bf(a.z * rms * wa.z) | ((unsigned)f2bf(a.w * rms * wa.w) << 16);
    o.z = (unsigned)f2bf(b.x * rms * wb.x) | ((unsigned)f2bf(b.y * rms * wb.y) << 16);
    o.w = (unsigned)f2bf(b.z * rms * wb.z) | ((unsigned)f2bf(b.w * rms * wb.w) << 16);
    *(uint4*)&hn[(size_t)row * D_MODEL + tid * 8] = o;
    return;
  }
  const float* in; u16* out; int Kd, Nd, lt;
  if (t < 4096) {
    const int m = t >> 10; lt = t & 1023;
    in  = m == 0 ? wq   : m == 1 ? wk   : m == 2 ? wv   : wo;
    out = m == 0 ? wq_t : m == 1 ? wk_t : m == 2 ? wv_t : wo_t;
    Kd = 2048; Nd = 2048;
  } else if (t < 12288) {
    const int m = (t - 4096) >> 12; lt = (t - 4096) & 4095;
    in = m == 0 ? wg : wu; out = m == 0 ? wg_t : wu_t;
    Kd = 2048; Nd = 8192;
  } else {
    lt = t - 12288; in = wd; out = wd_t; Kd = 8192; Nd = 2048;
  }
  const int ntx = Nd >> 6;
  const int n0 = (lt % ntx) * 64, k0 = (lt / ntx) * 64;
  const int r = tid >> 4, c4 = (tid & 15) * 4;
#pragma unroll
  for (int rr = 0; rr < 4; ++rr) {
    int kr = rr * 16 + r;
    float4 v = *(const float4*)&in[(size_t)(k0 + kr) * Nd + n0 + c4];
    tile[kr][c4 + 0] = v.x; tile[kr][c4 + 1] = v.y;
    tile[kr][c4 + 2] = v.z; tile[kr][c4 + 3] = v.w;
  }
  __syncthreads();
#pragma unroll
  for (int rr = 0; rr < 4; ++rr) {
    int nr = rr * 16 + r;
    uint2 o;
    o.x = (unsigned)f2bf(tile[c4 + 0][nr]) | ((unsigned)f2bf(tile[c4 + 1][nr]) << 16);
    o.y = (unsigned)f2bf(tile[c4 + 2][nr]) | ((unsigned)f2bf(tile[c4 + 3][nr]) << 16);
    *(uint2*)&out[(size_t)(n0 + nr) * Kd + k0 + c4] = o;
  }
}

// ---------------- staging: RN rows x 64 K into region (swizzled source) ----------------
template <int RN>
__device__ __forceinline__ void stage_op(const u16* src, int ldE,
                                         int row0, int ktbyte, u16* slot,
                                         int w, int lane) {
  constexpr int L = RN / 64;
#pragma unroll
  for (int l = 0; l < L; ++l) {
    const int dst = l * 8192 + w * 1024;
    const int dl = dst + lane * 16;
    const int srcb = dl ^ (((dl >> 7) & 7) << 4);
    const int row = srcb >> 7, colb = srcb & 127;
    gload_lds16((const char*)src + (size_t)(row0 + row) * ldE * 2 + ktbyte + colb,
                (char*)slot + dst);
  }
}

// ---------------- fused QKV GEMM: triple-B (BN=64), 2D super-tile mapping ----------------
__global__ __launch_bounds__(512, 1) void gemm_qkv(
    const u16* __restrict__ A, const u16* __restrict__ Bq,
    const u16* __restrict__ Bk, const u16* __restrict__ Bv,
    int M, int N, int K,
    u16* __restrict__ oq, u16* __restrict__ ok, u16* __restrict__ ovt,
    const float* __restrict__ fc, const float* __restrict__ fs) {
  extern __shared__ u16 smem[];
  const int tid = threadIdx.x;
  const int w = tid >> 6, lane = tid & 63;
  const int nwg = gridDim.x, bid = blockIdx.x;
  const int sw = (bid & 7) * (nwg >> 3) + (bid >> 3);
  // 2D super-tile: 4m x 8n per 32-block window (grid 512 = 16m x 32n)
  const int within = sw & 31, stile = sw >> 5;        // 16 stiles = 4mb x 4nb
  const int m0 = (((stile >> 2) << 2) + (within & 3)) * 256;
  const int n0 = (((stile & 3) << 3) + (within >> 2)) * 64;
  const int wm = w >> 1, wn = w & 1;
  const int KT = K / 64;
  const int ql = lane & 15, qh = (lane >> 4) * 16;
  f32x4 aq[4][2] = {}, ak[4][2] = {}, av[4][2] = {};

  auto stage = [&](int t, int slot) {
    u16* base = smem + slot * QKV_SLOT_U16;
    const int kb = t * 128;
    stage_op<256>(A,  K, m0, kb, base,          w, lane);
    stage_op<64>(Bq, K, n0, kb, base + 16384, w, lane);
    stage_op<64>(Bk, K, n0, kb, base + 20480, w, lane);
    stage_op<64>(Bv, K, n0, kb, base + 24576, w, lane);
  };

  stage(0, 0);
  for (int t = 0; t < KT; ++t) {
    if (t + 1 < KT) {
      stage(t + 1, (t + 1) & 1);
      asm volatile("s_waitcnt vmcnt(7)" ::: "memory");
    } else {
      asm volatile("s_waitcnt vmcnt(0)" ::: "memory");
    }
    __builtin_amdgcn_s_barrier();
    asm volatile("" ::: "memory");

    const u16* sA = smem + (t & 1) * QKV_SLOT_U16;
    const u16* sQ = sA + 16384;
    const u16* sK = sA + 20480;
    const u16* sV = sA + 24576;
#pragma unroll
    for (int kk = 0; kk < 2; ++kk) {
      bf16x8 af[4], bq[2], bk[2], bv[2];
      const int cb = kk * 64 + qh;
#pragma unroll
      for (int i = 0; i < 4; ++i) {
        const int row = wm * 64 + i * 16 + ql;
        af[i] = *(const bf16x8*)((const char*)sA + (((row << 7) + cb) ^ ((row & 7) << 4)));
      }
#pragma unroll
      for (int j = 0; j < 2; ++j) {
        const int row = wn * 32 + j * 16 + ql;
        const int byt = (((row << 7) + cb) ^ ((row & 7) << 4));
        bq[j] = *(const bf16x8*)((const char*)sQ + byt);
        bk[j] = *(const bf16x8*)((const char*)sK + byt);
        bv[j] = *(const bf16x8*)((const char*)sV + byt);
      }
      __builtin_amdgcn_s_setprio(1);
#pragma unroll
      for (int i = 0; i < 4; ++i)
#pragma unroll
        for (int j = 0; j < 2; ++j) {
          aq[i][j] = __builtin_amdgcn_mfma_f32_16x16x32_bf16(af[i], bq[j], aq[i][j], 0, 0, 0);
          ak[i][j] = __builtin_amdgcn_mfma_f32_16x16x32_bf16(af[i], bk[j], ak[i][j], 0, 0, 0);
          av[i][j] = __builtin_amdgcn_mfma_f32_16x16x32_bf16(af[i], bv[j], av[i][j], 0, 0, 0);
        }
      __builtin_amdgcn_s_setprio(0);
    }
    __builtin_amdgcn_s_barrier();
    asm volatile("" ::: "memory");
  }

  const int rbase = (lane >> 4) * 4;
#pragma unroll
  for (int i = 0; i < 4; ++i) {
#pragma unroll
    for (int j = 0; j < 2; ++j) {
      const int grow0 = m0 + wm * 64 + i * 16 + rbase;
      const int c = n0 + wn * 32 + j * 16 + ql;
      const int i2 = (c & 63) >> 1;
      const int odd = c & 1;
      {
        const int b = grow0 >> 11, s4 = grow0 & (S_LEN - 1);
        const int h = c >> 6, dh = c & 63;
        uint2 ov;
        ov.x = (unsigned)f2bf(av[i][j][0]) | ((unsigned)f2bf(av[i][j][1]) << 16);
        ov.y = (unsigned)f2bf(av[i][j][2]) | ((unsigned)f2bf(av[i][j][3]) << 16);
        *(uint2*)&ovt[((((size_t)b * NHEAD + h) * DHEAD + dh) << 11) + s4] = ov;
      }
#pragma unroll
      for (int r = 0; r < 4; ++r) {
        const int grow = grow0 + r;
        const int s4 = grow & (S_LEN - 1);
        const float cs = fc[s4 * 32 + i2], sn = fs[s4 * 32 + i2];
        {
          const float v = aq[i][j][r];
          const float p = __shfl_xor(v, 1);
          const float outv = odd ? (p * sn + v * cs) : (v * cs - p * sn);
          oq[(size_t)grow * D_MODEL + c] = f2bf(outv);
        }
        {
          const float v = ak[i][j][r];
          const float p = __shfl_xor(v, 1);
          const float outv = odd ? (p * sn + v * cs) : (v * cs - p * sn);
          ok[(size_t)grow * D_MODEL + c] = f2bf(outv);
        }
      }
    }
  }
}

// ---------------- fused gate+up GEMM: 4-phase pipelined (R15 schedule), 2D super-tile ----------------
__global__ __launch_bounds__(512, 1) void gemm_gu(
    const u16* __restrict__ A, const u16* __restrict__ Bg, const u16* __restrict__ Bu,
    int M, int N, int K, u16* __restrict__ o0) {
  extern __shared__ u16 smem[];
  const int tid = threadIdx.x;
  const int w = tid >> 6, lane = tid & 63;
  const int nwg = gridDim.x, bid = blockIdx.x;
  const int sw = (bid & 7) * (nwg >> 3) + (bid >> 3);
  // 2D super-tile: 4m x 8n per 32-block window (grid 1024 = 16m x 64n)
  const int within = sw & 31, stile = sw >> 5;        // 32 stiles = 4mb x 8nb
  const int m0 = (((stile >> 3) << 2) + (within & 3)) * 256;
  const int n0 = (((stile & 7) << 3) + (within >> 2)) * 128;
  const int wm = w >> 1, wn = w & 1;
  const int KT = K / 64;
  const int ql = lane & 15, qh = (lane >> 4) * 16;
  f32x4 accg[4][4] = {}, accu[4][4] = {};

  int abyt[4][2], bbyt[4][2];
#pragma unroll
  for (int i = 0; i < 4; ++i)
#pragma unroll
    for (int kk = 0; kk < 2; ++kk) {
      const int ra = wm * 64 + i * 16 + ql;
      abyt[i][kk] = ((ra << 7) + kk * 64 + qh) ^ ((ra & 7) << 4);
      const int rb = wn * 64 + i * 16 + ql;
      bbyt[i][kk] = ((rb << 7) + kk * 64 + qh) ^ ((rb & 7) << 4);
    }

  auto stage_E = [&](int t, int slot) {
    u16* base = smem + slot * 32768;
    stage_op<256>(A,  K, m0, t * 128, base,         w, lane);
    stage_op<128>(Bg, K, n0, t * 128, base + 16384, w, lane);
  };
  auto stage_L = [&](int t, int slot) {
    u16* base = smem + slot * 32768;
    stage_op<128>(Bu, K, n0, t * 128, base + 24576, w, lane);
  };

  stage_E(0, 0);
  stage_L(0, 0);
  asm volatile("s_waitcnt vmcnt(2)" ::: "memory");
  barrier_f();

  for (int t = 0; t < KT; ++t) {
    const bool last = (t == KT - 1);
    const char* sA = (const char*)smem + (t & 1) * 65536;
    const char* sG = sA + 32768;
    const char* sU = sA + 49152;
    bf16x8 af[4], bb[4];
#pragma unroll
    for (int i = 0; i < 4; ++i) af[i] = *(const bf16x8*)(sA + abyt[i][0]);
#pragma unroll
    for (int j = 0; j < 4; ++j) bb[j] = *(const bf16x8*)(sG + bbyt[j][0]);
    if (!last) {
      stage_E(t + 1, (t + 1) & 1);
      asm volatile("s_waitcnt vmcnt(6)" ::: "memory");
    } else {
      asm volatile("s_waitcnt vmcnt(0)" ::: "memory");
    }
    barrier_f();
    __builtin_amdgcn_s_setprio(1);
#pragma unroll
    for (int i = 0; i < 4; ++i)
#pragma unroll
      for (int j = 0; j < 4; ++j)
        accg[i][j] = __builtin_amdgcn_mfma_f32_16x16x32_bf16(af[i], bb[j], accg[i][j], 0, 0, 0);
    __builtin_amdgcn_s_setprio(0);
    barrier_f();
#pragma unroll
    for (int j = 0; j < 4; ++j) bb[j] = *(const bf16x8*)(sU + bbyt[j][0]);
    if (!last) stage_L(t + 1, (t + 1) & 1);
    barrier_f();
    __builtin_amdgcn_s_setprio(1);
#pragma unroll
    for (int i = 0; i < 4; ++i)
#pragma unroll
      for (int j = 0; j < 4; ++j)
        accu[i][j] = __builtin_amdgcn_mfma_f32_16x16x32_bf16(af[i], bb[j], accu[i][j], 0, 0, 0);
    __builtin_amdgcn_s_setprio(0);
    barrier_f();
#pragma unroll
    for (int i = 0; i < 4; ++i) af[i] = *(const bf16x8*)(sA + abyt[i][1]);
#pragma unroll
    for (int j = 0; j < 4; ++j) bb[j] = *(const bf16x8*)(sG + bbyt[j][1]);
    barrier_f();
    __builtin_amdgcn_s_setprio(1);
#pragma unroll
    for (int i = 0; i < 4; ++i)
#pragma unroll
      for (int j = 0; j < 4; ++j)
        accg[i][j] = __builtin_amdgcn_mfma_f32_16x16x32_bf16(af[i], bb[j], accg[i][j], 0, 0, 0);
    __builtin_amdgcn_s_setprio(0);
    barrier_f();
#pragma unroll
    for (int j = 0; j < 4; ++j) bb[j] = *(const bf16x8*)(sU + bbyt[j][1]);
    if (!last) asm volatile("s_waitcnt vmcnt(2)" ::: "memory");
    barrier_f();
    __builtin_amdgcn_s_setprio(1);
#pragma unroll
    for (int i = 0; i < 4; ++i)
#pragma unroll
      for (int j = 0; j < 4; ++j)
        accu[i][j] = __builtin_amdgcn_mfma_f32_16x16x32_bf16(af[i], bb[j], accu[i][j], 0, 0, 0);
    __builtin_amdgcn_s_setprio(0);
    barrier_f();
  }

  const int rbase = (lane >> 4) * 4;
#pragma unroll
  for (int i = 0; i < 4; ++i) {
#pragma unroll
    for (int j = 0; j < 4; ++j) {
      const int grow0 = m0 + wm * 64 + i * 16 + rbase;
      const int gcol = n0 + wn * 64 + j * 16 + ql;
#pragma unroll
      for (int r = 0; r < 4; ++r) {
        const float g = accg[i][j][r];
        const float u = accu[i][j][r];
        const float sg = g / (1.f + __expf(-g));
        o0[(size_t)(grow0 + r) * N + gcol] = f2bf(sg * u);
      }
    }
  }
}

// ---------------- split-K GEMM: ring-2, 256x256, split-K=2, 2D super-tile ----------------
__global__ __launch_bounds__(512, 1) void gemm_dn(
    const u16* __restrict__ A, const u16* __restrict__ Bt,
    int M, int N, int Kld, u16* __restrict__ pbuf) {
  extern __shared__ u16 smem[];
  const int tid = threadIdx.x;
  const int w = tid >> 6, lane = tid & 63;
  const int nwg = gridDim.x, bid = blockIdx.x;
  const int sw = (bid & 7) * (nwg >> 3) + (bid >> 3);
  const int mtiles = M / 256;
  const int tilesPerSplit = mtiles * (N / 256);       // 128
  const int split = sw / tilesPerSplit;
  const int tt = sw % tilesPerSplit;
  // 2D super-tile: 4m x 8n per 32-block window (128 tiles = 16m x 8n)
  const int within = tt & 31, stile = tt >> 5;        // 4 stiles = 4 m-bands
  const int m0 = ((stile << 2) + (within & 3)) * 256;
  const int n0 = (within >> 2) * 256;
  const u16* Ap = A + (size_t)split * (Kld / 2);
  const u16* Bp = Bt + (size_t)split * (Kld / 2);
  u16* op = pbuf + (size_t)split * M * N;
  const int wm = w >> 2, wn = w & 3;
  const int KT = (Kld / 2) / 64;
  const int ql = lane & 15, qh = (lane >> 4) * 16;
  f32x4 acc[8][4] = {};

  auto stage = [&](int t, int slot) {
    u16* base = smem + slot * 32768;
    const int kb = t * 128;
    stage_op<256>(Ap, Kld, m0, kb, base,         w, lane);
    stage_op<256>(Bp, Kld, n0, kb, base + 16384, w, lane);
  };

  stage(0, 0);
  for (int t = 0; t < KT; ++t) {
    if (t + 1 < KT) {
      stage(t + 1, (t + 1) & 1);
      asm volatile("s_waitcnt vmcnt(8)" ::: "memory");
    } else {
      asm volatile("s_waitcnt vmcnt(0)" ::: "memory");
    }
    __builtin_amdgcn_s_barrier();
    asm volatile("" ::: "memory");

    const u16* sA = smem + (t & 1) * 32768;
    const u16* sB = sA + 16384;
#pragma unroll
    for (int kk = 0; kk < 2; ++kk) {
      bf16x8 af[8], bq[4];
      const int cb = kk * 64 + qh;
#pragma unroll
      for (int i = 0; i < 8; ++i) {
        const int row = wm * 128 + i * 16 + ql;
        af[i] = *(const bf16x8*)((const char*)sA + (((row << 7) + cb) ^ ((row & 7) << 4)));
      }
#pragma unroll
      for (int j = 0; j < 4; ++j) {
        const int row = wn * 64 + j * 16 + ql;
        bq[j] = *(const bf16x8*)((const char*)sB + (((row << 7) + cb) ^ ((row & 7) << 4)));
      }
      __builtin_amdgcn_s_setprio(1);
#pragma unroll
      for (int i = 0; i < 8; ++i)
#pragma unroll
        for (int j = 0; j < 4; ++j)
          acc[i][j] = __builtin_amdgcn_mfma_f32_16x16x32_bf16(af[i], bq[j], acc[i][j], 0, 0, 0);
      __builtin_amdgcn_s_setprio(0);
    }
    __builtin_amdgcn_s_barrier();
    asm volatile("" ::: "memory");
  }

  const int rbase = (lane >> 4) * 4;
#pragma unroll
  for (int i = 0; i < 8; ++i) {
#pragma unroll
    for (int j = 0; j < 4; ++j) {
      const int grow0 = m0 + wm * 128 + i * 16 + rbase;
      const int gcol = n0 + wn * 64 + j * 16 + ql;
#pragma unroll
      for (int r = 0; r < 4; ++r)
        op[(size_t)(grow0 + r) * N + gcol] = f2bf(acc[i][j][r]);
    }
  }
}

// ---------------- down combine: out += p0 + p1 (bf16 partials) ----------------
__global__ __launch_bounds__(256) void combine_kernel(
    const u16* __restrict__ p0, const u16* __restrict__ p1, float* __restrict__ out) {
  const size_t idx = ((size_t)blockIdx.x * 256 + threadIdx.x) * 8;
  bf16x8 a = *(const bf16x8*)&p0[idx];
  bf16x8 b = *(const bf16x8*)&p1[idx];
  float4 c0 = *(const float4*)&out[idx];
  float4 c1 = *(const float4*)&out[idx + 4];
  c0.x += bf2f((u16)a[0]) + bf2f((u16)b[0]);
  c0.y += bf2f((u16)a[1]) + bf2f((u16)b[1]);
  c0.z += bf2f((u16)a[2]) + bf2f((u16)b[2]);
  c0.w += bf2f((u16)a[3]) + bf2f((u16)b[3]);
  c1.x += bf2f((u16)a[4]) + bf2f((u16)b[4]);
  c1.y += bf2f((u16)a[5]) + bf2f((u16)b[5]);
  c1.z += bf2f((u16)a[6]) + bf2f((u16)b[6]);
  c1.w += bf2f((u16)a[7]) + bf2f((u16)b[7]);
  *(float4*)&out[idx] = c0;
  *(float4*)&out[idx + 4] = c1;
}

// ---------------- O-proj combine + residual + fused rmsnorm2 ----------------
__global__ __launch_bounds__(256) void combine_o_norm(
    const u16* __restrict__ p0, const u16* __restrict__ p1,
    const float* __restrict__ x, const float* __restrict__ wt,
    float* __restrict__ out, u16* __restrict__ hn) {
  const int row = blockIdx.x;
  const int tid = threadIdx.x;
  const size_t base = (size_t)row * D_MODEL + tid * 8;
  bf16x8 a = *(const bf16x8*)&p0[base];
  bf16x8 b = *(const bf16x8*)&p1[base];
  float4 x0 = *(const float4*)&x[base];
  float4 x1 = *(const float4*)&x[base + 4];
  float c[8];
  c[0] = x0.x + bf2f((u16)a[0]) + bf2f((u16)b[0]);
  c[1] = x0.y + bf2f((u16)a[1]) + bf2f((u16)b[1]);
  c[2] = x0.z + bf2f((u16)a[2]) + bf2f((u16)b[2]);
  c[3] = x0.w + bf2f((u16)a[3]) + bf2f((u16)b[3]);
  c[4] = x1.x + bf2f((u16)a[4]) + bf2f((u16)b[4]);
  c[5] = x1.y + bf2f((u16)a[5]) + bf2f((u16)b[5]);
  c[6] = x1.z + bf2f((u16)a[6]) + bf2f((u16)b[6]);
  c[7] = x1.w + bf2f((u16)a[7]) + bf2f((u16)b[7]);
  float4 o0 = {c[0], c[1], c[2], c[3]};
  float4 o1 = {c[4], c[5], c[6], c[7]};
  *(float4*)&out[base] = o0;
  *(float4*)&out[base + 4] = o1;
  float ss = 0.f;
#pragma unroll
  for (int e = 0; e < 8; ++e) ss += c[e] * c[e];
#pragma unroll
  for (int d = 1; d < 64; d <<= 1) ss += __shfl_xor(ss, d);
  __shared__ float red[4];
  if ((tid & 63) == 0) red[tid >> 6] = ss;
  __syncthreads();
  const float tot = red[0] + red[1] + red[2] + red[3];
  const float rms = rsqrtf(tot * (1.f / (float)D_MODEL) + 1e-6f);
  float4 wa = *(const float4*)&wt[tid * 8];
  float4 wb = *(const float4*)&wt[tid * 8 + 4];
  uint4 o;
  o.x = (unsigned)f2bf(c[0] * rms * wa.x) | ((unsigned)f2bf(c[1] * rms * wa.y) << 16);
  o.y = (unsigned)f2bf(c[2] * rms * wa.z) | ((unsigned)f2bf(c[3] * rms * wa.w) << 16);
  o.z = (unsigned)f2bf(c[4] * rms * wb.x) | ((unsigned)f2bf(c[5] * rms * wb.y) << 16);
  o.w = (unsigned)f2bf(c[6] * rms * wb.z) | ((unsigned)f2bf(c[7] * rms * wb.w) << 16);
  *(uint4*)&hn[base] = o;
}

// ---------------- Flash attention (causal), swapped-QK^T, swizzled, ring-2, defer-max ----------------
__global__ __launch_bounds__(256) void attn_kernel(
    const u16* __restrict__ q, const u16* __restrict__ k,
    const u16* __restrict__ vt, u16* __restrict__ o) {
  __shared__ u16 lKV[2][128 * 64];
  __shared__ u16 lP[4][32 * 64];
  const int tid = threadIdx.x, w = tid >> 6, lane = tid & 63;
  const int ql = lane & 15, qh16 = (lane >> 4) * 16, rbase = (lane >> 4) * 4;
  const int bx = (int)gridDim.x - 1 - (int)blockIdx.x;
  const int bh = blockIdx.y, b = bh >> 5, h = bh & 31;
  const int q0 = bx * 128;
  const int nt = 2 * bx + 2;
  const char* kbase = (const char*)(k + ((size_t)b * S_LEN) * D_MODEL + h * DHEAD);
  const char* vbase = (const char*)(vt + (size_t)bh * DHEAD * S_LEN);

  bf16x8 qf[2][2];
#pragma unroll
  for (int i = 0; i < 2; ++i) {
    const size_t tok = (size_t)b * S_LEN + q0 + w * 32 + i * 16 + ql;
#pragma unroll
    for (int kk = 0; kk < 2; ++kk) {
      bf16x8 v = *(const bf16x8*)&q[tok * D_MODEL + h * DHEAD + kk * 32 + (lane >> 4) * 8];
#pragma unroll
      for (int e = 0; e < 8; ++e) v[e] = (short)f2bf(bf2f((u16)v[e]) * 0.125f);
      qf[i][kk] = v;
    }
  }

  float m[2] = {-1e30f, -1e30f}, l[2] = {0.f, 0.f};
  f32x4 oacc[2][4] = {};

  auto stage = [&](int kt, int slot) {
    const int s0 = kt * 64;
#pragma unroll
    for (int lo = 0; lo < 2; ++lo) {
      const int dst = lo * 4096 + w * 1024;
      const int dl = dst + lane * 16;
      const int srcb = dl ^ (((dl >> 7) & 7) << 4);
      const int row = srcb >> 7, colb = srcb & 127;
      gload_lds16(kbase + (size_t)(s0 + row) * (D_MODEL * 2) + colb,
                  (char*)&lKV[slot][0] + dst);
    }
#pragma unroll
    for (int lo = 0; lo < 2; ++lo) {
      const int dst = lo * 4096 + w * 1024;
      const int dl = dst + lane * 16;
      const int srcb = dl ^ (((dl >> 7) & 7) << 4);
      const int row = srcb >> 7, colb = srcb & 127;
      gload_lds16(vbase + (size_t)row * (S_LEN * 2) + (size_t)s0 * 2 + colb,
                  (char*)&lKV[slot][64 * 64] + dst);
    }
  };

  stage(0, 0);
  for (int kt = 0; kt < nt; ++kt) {
    if (kt + 1 < nt) {
      stage(kt + 1, (kt + 1) & 1);
      asm volatile("s_waitcnt vmcnt(4)" ::: "memory");
    } else {
      asm volatile("s_waitcnt vmcnt(0)" ::: "memory");
    }
    __builtin_amdgcn_s_barrier();
    asm volatile("" ::: "memory");

    const u16* sK = &lKV[kt & 1][0];
    const u16* sV = &lKV[kt & 1][64 * 64];
    const int s0 = kt * 64;

    f32x4 scT[2][4] = {};
#pragma unroll
    for (int kk = 0; kk < 2; ++kk) {
#pragma unroll
      for (int j = 0; j < 4; ++j) {
        const int row = j * 16 + ql;
        bf16x8 kf = *(const bf16x8*)((const char*)sK +
                      (((row << 7) + kk * 64 + qh16) ^ ((row & 7) << 4)));
#pragma unroll
        for (int i = 0; i < 2; ++i)
          scT[i][j] = __builtin_amdgcn_mfma_f32_16x16x32_bf16(kf, qf[i][kk], scT[i][j], 0, 0, 0);
      }
    }
    const bool diag = (s0 + 63 > q0);
#pragma unroll
    for (int i = 0; i < 2; ++i) {
      const int qrow = q0 + w * 32 + i * 16 + ql;
      if (diag) {
#pragma unroll
        for (int j = 0; j < 4; ++j)
#pragma unroll
          for (int r = 0; r < 4; ++r)
            if (s0 + j * 16 + rbase + r > qrow) scT[i][j][r] = -1e30f;
      }
      float mx = scT[i][0][0];
#pragma unroll
      for (int j = 0; j < 4; ++j)
#pragma unroll
        for (int r = 0; r < 4; ++r) mx = fmaxf(mx, scT[i][j][r]);
      mx = fmaxf(mx, __shfl_xor(mx, 16));
      mx = fmaxf(mx, __shfl_xor(mx, 32));
      float alpha = 1.f;
      if (!__all(mx - m[i] <= 8.f)) {
        const float mnew = fmaxf(m[i], mx);
        alpha = __expf(m[i] - mnew);
        m[i] = mnew;
#pragma unroll
        for (int rr = 0; rr < 4; ++rr) {
          const float ar = __shfl(alpha, rbase + rr);
#pragma unroll
          for (int j = 0; j < 4; ++j) oacc[i][j][rr] *= ar;
        }
      }
      float rs = 0.f;
#pragma unroll
      for (int j = 0; j < 4; ++j)
#pragma unroll
        for (int r = 0; r < 4; ++r) {
          const float p = __expf(scT[i][j][r] - m[i]);
          scT[i][j][r] = p;
          rs += p;
        }
      rs += __shfl_xor(rs, 16);
      rs += __shfl_xor(rs, 32);
      l[i] = l[i] * alpha + rs;
      const int prow = i * 16 + ql;
      const int pb = prow << 7;
      const int swz = (prow & 7) << 4;
#pragma unroll
      for (int j = 0; j < 4; ++j) {
#pragma unroll
        for (int rp = 0; rp < 2; ++rp) {
          const int col = j * 16 + rbase + rp * 2;
          unsigned pk = (unsigned)f2bf(scT[i][j][rp * 2]) |
                        ((unsigned)f2bf(scT[i][j][rp * 2 + 1]) << 16);
          *(unsigned*)((char*)lP[w] + ((pb + col * 2) ^ swz)) = pk;
        }
      }
    }
#pragma unroll
    for (int i = 0; i < 2; ++i) {
      const int arow = i * 16 + ql;
#pragma unroll
      for (int kk = 0; kk < 2; ++kk) {
        bf16x8 pa = *(const bf16x8*)((const char*)lP[w] +
                      (((arow << 7) + kk * 64 + qh16) ^ ((arow & 7) << 4)));
#pragma unroll
        for (int j = 0; j < 4; ++j) {
          const int vrow = j * 16 + ql;
          bf16x8 bv = *(const bf16x8*)((const char*)sV +
                        (((vrow << 7) + kk * 64 + qh16) ^ ((vrow & 7) << 4)));
          oacc[i][j] = __builtin_amdgcn_mfma_f32_16x16x32_bf16(pa, bv, oacc[i][j], 0, 0, 0);
        }
      }
    }
    __builtin_amdgcn_s_barrier();
    asm volatile("" ::: "memory");
  }
#pragma unroll
  for (int i = 0; i < 2; ++i) {
#pragma unroll
    for (int rr = 0; rr < 4; ++rr) {
      const float linv = 1.f / __shfl(l[i], rbase + rr);
      const size_t tok = (size_t)b * S_LEN + q0 + w * 32 + i * 16 + rbase + rr;
#pragma unroll
      for (int j = 0; j < 4; ++j)
        o[tok * D_MODEL + h * DHEAD + j * 16 + ql] = f2bf(oacc[i][j][rr] * linv);
    }
  }
}

// ---------------- host ----------------
extern "C" void kernel_launch(void* const* d_in, const int* in_sizes, int n_in,
                              void* d_out, int out_size, void* d_ws, size_t ws_size,
                              hipStream_t stream) {
  (void)in_sizes; (void)n_in; (void)out_size; (void)ws_size;
  const float* x  = (const float*)d_in[0];
  const float* fc = (const float*)d_in[1];
  const float* fs = (const float*)d_in[2];
  const float* wq = (const float*)d_in[4];
  const float* wk = (const float*)d_in[5];
  const float* wv = (const float*)d_in[6];
  const float* wo = (const float*)d_in[7];
  const float* wg = (const float*)d_in[8];
  const float* wu = (const float*)d_in[9];
  const float* wd = (const float*)d_in[10];
  const float* n1 = (const float*)d_in[11];
  const float* n2 = (const float*)d_in[12];
  float* out = (float*)d_out;

  char* ws = (char*)d_ws;
  size_t off = 0;
  auto alloc = [&](size_t bytes) { void* p = ws + off; off += (bytes + 255) & ~(size_t)255; return p; };
  u16* wq_t = (u16*)alloc((size_t)D_MODEL * D_MODEL * 2);
  u16* wk_t = (u16*)alloc((size_t)D_MODEL * D_MODEL * 2);
  u16* wv_t = (u16*)alloc((size_t)D_MODEL * D_MODEL * 2);
  u16* wo_t = (u16*)alloc((size_t)D_MODEL * D_MODEL * 2);
  u16* wg_t = (u16*)alloc((size_t)D_MODEL * FF_DIM * 2);
  u16* wu_t = (u16*)alloc((size_t)D_MODEL * FF_DIM * 2);
  u16* wd_t = (u16*)alloc((size_t)FF_DIM * D_MODEL * 2);
  u16* hn   = (u16*)alloc((size_t)NTOK * D_MODEL * 2);
  u16* qb   = (u16*)alloc((size_t)NTOK * D_MODEL * 2);
  u16* kb   = (u16*)alloc((size_t)NTOK * D_MODEL * 2);
  u16* vtb  = (u16*)alloc((size_t)NTOK * D_MODEL * 2);
  u16* ao   = (u16*)alloc((size_t)NTOK * D_MODEL * 2);
  u16* gt   = (u16*)alloc((size_t)NTOK * FF_DIM * 2);
  u16* pbuf = qb;   // bf16 split-K partials reuse dead qb/kb region

  wconv_all<<<16384 + NTOK, 256, 0, stream>>>(wq, wk, wv, wo, wg, wu, wd,
                                              wq_t, wk_t, wv_t, wo_t, wg_t, wu_t, wd_t,
                                              x, n1, hn);
  gemm_qkv<<<512, 512, QKV_LDS_BYTES, stream>>>(hn, wq_t, wk_t, wv_t,
                                                NTOK, D_MODEL, D_MODEL,
                                                qb, kb, vtb, fc, fs);
  attn_kernel<<<dim3(16, 64), 256, 0, stream>>>(qb, kb, vtb, ao);
  gemm_dn<<<256, 512, DN_LDS_BYTES, stream>>>(ao, wo_t, NTOK, D_MODEL, D_MODEL, pbuf);
  combine_o_norm<<<NTOK, 256, 0, stream>>>(pbuf, pbuf + (size_t)NTOK * D_MODEL,
                                           x, n2, out, hn);
  gemm_gu<<<1024, 512, GU_LDS_BYTES, stream>>>(hn, wg_t, wu_t, NTOK, FF_DIM, D_MODEL, gt);
  gemm_dn<<<256, 512, DN_LDS_BYTES, stream>>>(gt, wd_t, NTOK, D_MODEL, FF_DIM, pbuf);
  combine_kernel<<<(NTOK * D_MODEL) / (256 * 8), 256, 0, stream>>>(
      pbuf, pbuf + (size_t)NTOK * D_MODEL, out);
}